// Round 3
// baseline (355.630 us; speedup 1.0000x reference)
//
#include <hip/hip_runtime.h>
#include <cstddef>

#define EPS_ 1e-5f
#define SCALE_ 0.1767766952966369f   // 1/sqrt(32)

__device__ __forceinline__ float gelu_f(float x) {
    return 0.5f * x * (1.0f + erff(x * 0.7071067811865476f));
}

// -------- LayerNorm over C=256, one wave per row --------
__global__ __launch_bounds__(256) void ln_kernel(const float* __restrict__ x,
                                                 const float* __restrict__ g,
                                                 const float* __restrict__ b,
                                                 float* __restrict__ out) {
    int wid = threadIdx.x >> 6, lane = threadIdx.x & 63;
    int row = blockIdx.x * 4 + wid;
    const float4 xv = *(const float4*)(x + (size_t)row * 256 + lane * 4);
    float s  = xv.x + xv.y + xv.z + xv.w;
    float sq = xv.x*xv.x + xv.y*xv.y + xv.z*xv.z + xv.w*xv.w;
#pragma unroll
    for (int m = 1; m < 64; m <<= 1) { s += __shfl_xor(s, m); sq += __shfl_xor(sq, m); }
    float mean = s * (1.0f/256.0f);
    float var  = sq * (1.0f/256.0f) - mean*mean;
    float rstd = rsqrtf(var + EPS_);
    float4 gv = *(const float4*)(g + lane*4);
    float4 bv = *(const float4*)(b + lane*4);
    float4 o;
    o.x = (xv.x-mean)*rstd*gv.x + bv.x;
    o.y = (xv.y-mean)*rstd*gv.y + bv.y;
    o.z = (xv.z-mean)*rstd*gv.z + bv.z;
    o.w = (xv.w-mean)*rstd*gv.w + bv.w;
    *(float4*)(out + (size_t)row * 256 + lane * 4) = o;
}

// -------- Generic tiled f32 GEMM: C = A[M,K] @ B[K,N] (+bias)(gelu)(+resid) --------
template<bool BIAS, bool GACT, bool RESID, int KSPLIT>
__global__ __launch_bounds__(256) void gemm_kernel(
    const float* __restrict__ A, const float* __restrict__ Bm,
    const float* __restrict__ bias, const float* __restrict__ resid,
    float* __restrict__ Cout, int M, int N, int K) {
    __shared__ float As[16][68];
    __shared__ float Bs[16][64];
    int t = threadIdx.x;
    int bm = blockIdx.x, bn = blockIdx.y, kz = blockIdx.z;
    int kchunk = K / KSPLIT;
    int k0 = kz * kchunk;
    int tm = t >> 4, tn = t & 15;
    int la_m = t >> 2, la_k = (t & 3) << 2;
    int lb_k = t >> 4, lb_n = (t & 15) << 2;
    float acc[4][4] = {};
    const float* Aptr = A  + (size_t)(bm*64 + la_m) * K + k0 + la_k;
    const float* Bptr = Bm + (size_t)(k0 + lb_k) * N + bn*64 + lb_n;
    for (int kk = 0; kk < kchunk; kk += 16) {
        float4 a4 = *(const float4*)(Aptr + kk);
        float4 b4 = *(const float4*)(Bptr + (size_t)kk * N);
        __syncthreads();
        As[la_k+0][la_m] = a4.x;
        As[la_k+1][la_m] = a4.y;
        As[la_k+2][la_m] = a4.z;
        As[la_k+3][la_m] = a4.w;
        *(float4*)(&Bs[lb_k][lb_n]) = b4;
        __syncthreads();
#pragma unroll
        for (int k = 0; k < 16; ++k) {
            float4 av = *(const float4*)(&As[k][tm<<2]);
            float4 bv = *(const float4*)(&Bs[k][tn<<2]);
            acc[0][0] += av.x*bv.x; acc[0][1] += av.x*bv.y; acc[0][2] += av.x*bv.z; acc[0][3] += av.x*bv.w;
            acc[1][0] += av.y*bv.x; acc[1][1] += av.y*bv.y; acc[1][2] += av.y*bv.z; acc[1][3] += av.y*bv.w;
            acc[2][0] += av.z*bv.x; acc[2][1] += av.z*bv.y; acc[2][2] += av.z*bv.z; acc[2][3] += av.z*bv.w;
            acc[3][0] += av.w*bv.x; acc[3][1] += av.w*bv.y; acc[3][2] += av.w*bv.z; acc[3][3] += av.w*bv.w;
        }
    }
    int row0 = bm*64 + tm*4, col0 = bn*64 + tn*4;
    float4 bv4 = make_float4(0.f,0.f,0.f,0.f);
    if (BIAS) bv4 = *(const float4*)(bias + col0);
#pragma unroll
    for (int i2 = 0; i2 < 4; ++i2) {
        float4 r;
        r.x = acc[i2][0]; r.y = acc[i2][1]; r.z = acc[i2][2]; r.w = acc[i2][3];
        if (BIAS) { r.x += bv4.x; r.y += bv4.y; r.z += bv4.z; r.w += bv4.w; }
        if (GACT) { r.x = gelu_f(r.x); r.y = gelu_f(r.y); r.z = gelu_f(r.z); r.w = gelu_f(r.w); }
        if (RESID) {
            float4 rv = *(const float4*)(resid + (size_t)(row0+i2)*N + col0);
            r.x += rv.x; r.y += rv.y; r.z += rv.z; r.w += rv.w;
        }
        float* dst = Cout + (KSPLIT > 1 ? (size_t)kz * M * N : (size_t)0) + (size_t)(row0+i2)*N + col0;
        *(float4*)dst = r;
    }
}

// -------- qk[bi][h][j] = q_i^h . k_j^h ; block = (i-tile 32, h, b), k staged in LDS --------
__global__ __launch_bounds__(256) void qk_kernel(const float* __restrict__ qkv,
                                                 float* __restrict__ qk) {
    __shared__ float k_lds[512*32];   // 64 KB
    int t = threadIdx.x;
    int it = blockIdx.x;              // 0..15
    int h  = blockIdx.y;              // 0..7
    int b  = blockIdx.z;              // 0..1
    const float* base = qkv + (size_t)b * 393216;
    // stage k[b, :, h*32:(h+1)*32]
#pragma unroll
    for (int r = 0; r < 16; ++r) {
        int idx = r*256 + t;
        int row = idx >> 3, c4 = idx & 7;
        float4 kv = *(const float4*)(base + (size_t)row*768 + 256 + h*32 + c4*4);
        *(float4*)(k_lds + row*32 + c4*4) = kv;
    }
    __syncthreads();
    int ir = t & 31, jg = t >> 5;     // thread: row i0+ir, j-slice jg*64..+63
    int i = it*32 + ir;
    // q row into registers (8 float4 = 32 VGPR)
    float4 q[8];
    const float* qp = base + (size_t)i*768 + h*32;
#pragma unroll
    for (int c4 = 0; c4 < 8; ++c4) q[c4] = *(const float4*)(qp + c4*4);
    float* outp = qk + (((size_t)(b*512 + i))*8 + h)*512 + jg*64;
    for (int jj = 0; jj < 64; jj += 4) {
        float a4[4];
#pragma unroll
        for (int u = 0; u < 4; ++u) {
            const float* kp = k_lds + (size_t)(jg*64 + jj + u)*32;
            float acc = 0.f;
#pragma unroll
            for (int c4 = 0; c4 < 8; ++c4) {
                float4 kv = *(const float4*)(kp + c4*4);
                acc += q[c4].x*kv.x + q[c4].y*kv.y + q[c4].z*kv.z + q[c4].w*kv.w;
            }
            a4[u] = acc;
        }
        *(float4*)(outp + jj) = make_float4(a4[0], a4[1], a4[2], a4[3]);
    }
}

// -------- Fused rel-bias + logits + softmax. Block = (b,i); thread owns j. --------
// attn[bi][h][j] = softmax_j( (qk[bi][h][j] + LN(GELU(rp[bi,j,:]@w_rel + b_rel))[h]) * scale )
__global__ __launch_bounds__(256) void rel_softmax_kernel(
    const float* __restrict__ rp, const float* __restrict__ qk,
    const float* __restrict__ w_rel, const float* __restrict__ b_rel,
    const float* __restrict__ g_reln, const float* __restrict__ b_reln,
    float* __restrict__ attn) {
    __shared__ float w_lds[256*8];    // 8 KB, [c][h]
    __shared__ float lg_lds[8*512];   // 16 KB, [h][j]
    int t = threadIdx.x;
    int bi = blockIdx.x;
    {   // stage w_rel (512 float4, 2 rounds)
        const float4* wsrc = (const float4*)w_rel;
        float4* wdst = (float4*)w_lds;
        wdst[t]       = wsrc[t];
        wdst[t + 256] = wsrc[t + 256];
    }
    float br[8], gr[8], bn[8];
#pragma unroll
    for (int h = 0; h < 8; ++h) { br[h] = b_rel[h]; gr[h] = g_reln[h]; bn[h] = b_reln[h]; }
    __syncthreads();
    for (int rep = 0; rep < 2; ++rep) {
        int j = t + rep*256;
        const float4* rrow = (const float4*)(rp + ((size_t)bi*512 + j)*256);
        float rel8[8] = {0.f,0.f,0.f,0.f,0.f,0.f,0.f,0.f};
        for (int ls = 0; ls < 16; ++ls) {      // 16 × 64B-line steps
            float buf[16];
            *(float4*)(buf +  0) = rrow[ls*4 + 0];
            *(float4*)(buf +  4) = rrow[ls*4 + 1];
            *(float4*)(buf +  8) = rrow[ls*4 + 2];
            *(float4*)(buf + 12) = rrow[ls*4 + 3];
#pragma unroll
            for (int e = 0; e < 16; ++e) {
                const float* wp = w_lds + (size_t)(ls*16 + e)*8;
                float4 w0 = *(const float4*)(wp);
                float4 w1 = *(const float4*)(wp + 4);
                float rv = buf[e];
                rel8[0] += rv*w0.x; rel8[1] += rv*w0.y; rel8[2] += rv*w0.z; rel8[3] += rv*w0.w;
                rel8[4] += rv*w1.x; rel8[5] += rv*w1.y; rel8[6] += rv*w1.z; rel8[7] += rv*w1.w;
            }
        }
        // GELU (exact) then LayerNorm over H=8, all in-lane
        float gvv[8];
#pragma unroll
        for (int h = 0; h < 8; ++h) {
            float valg = rel8[h] + br[h];
            gvv[h] = 0.5f * valg * (1.0f + erff(valg * 0.7071067811865476f));
        }
        float sm = 0.f, sq = 0.f;
#pragma unroll
        for (int h = 0; h < 8; ++h) { sm += gvv[h]; sq += gvv[h]*gvv[h]; }
        float mean = sm * 0.125f;
        float var  = sq * 0.125f - mean*mean;
        float rstd = rsqrtf(var + EPS_);
        const float* qrow = qk + (size_t)bi*4096 + j;
#pragma unroll
        for (int h = 0; h < 8; ++h) {
            float reln = (gvv[h] - mean) * rstd * gr[h] + bn[h];
            lg_lds[h*512 + j] = (qrow[(size_t)h*512] + reln) * SCALE_;
        }
    }
    __syncthreads();
    // fused softmax: half-wave (32 lanes) per head row
    {
        int w = t >> 6, l = t & 63;
        int h = w*2 + (l >> 5);
        int sub = l & 31;
        float* row = lg_lds + h*512 + sub*16;
        float v[16];
        *(float4*)(v +  0) = *(float4*)(row + 0);
        *(float4*)(v +  4) = *(float4*)(row + 4);
        *(float4*)(v +  8) = *(float4*)(row + 8);
        *(float4*)(v + 12) = *(float4*)(row + 12);
        float mx = v[0];
#pragma unroll
        for (int e = 1; e < 16; ++e) mx = fmaxf(mx, v[e]);
#pragma unroll
        for (int m = 1; m < 32; m <<= 1) mx = fmaxf(mx, __shfl_xor(mx, m));
        float s = 0.f;
#pragma unroll
        for (int e = 0; e < 16; ++e) { v[e] = expf(v[e] - mx); s += v[e]; }
#pragma unroll
        for (int m = 1; m < 32; m <<= 1) s += __shfl_xor(s, m);
        float inv = 1.0f / s;
#pragma unroll
        for (int e = 0; e < 16; ++e) v[e] *= inv;
        float* dst = attn + (size_t)bi*4096 + h*512 + sub*16;
        *(float4*)(dst +  0) = *(float4*)(v +  0);
        *(float4*)(dst +  4) = *(float4*)(v +  4);
        *(float4*)(dst +  8) = *(float4*)(v +  8);
        *(float4*)(dst + 12) = *(float4*)(v + 12);
    }
}

// -------- o = attn @ v. Block = 4 bi rows (attn in LDS); thread owns out column c. --------
__global__ __launch_bounds__(256) void attnv_kernel(const float* __restrict__ attn,
                                                    const float* __restrict__ qkv,
                                                    float* __restrict__ o) {
    __shared__ float a_lds[4*8*512];  // 64 KB
    int t = threadIdx.x;
    int bi0 = blockIdx.x * 4;
    int b = bi0 >> 9;
    const float4* asrc = (const float4*)(attn + (size_t)bi0*4096);
    float4* adst = (float4*)a_lds;
#pragma unroll
    for (int r = 0; r < 16; ++r) adst[r*256 + t] = asrc[r*256 + t];
    __syncthreads();
    int c = t, h = c >> 5;
    const float* vcol = qkv + (size_t)b*393216 + 512 + c;
    float acc0 = 0.f, acc1 = 0.f, acc2 = 0.f, acc3 = 0.f;
    for (int j = 0; j < 512; j += 2) {
        float vv0 = vcol[(size_t)j*768];
        float vv1 = vcol[(size_t)(j+1)*768];
        acc0 += a_lds[(0*8+h)*512 + j]*vv0 + a_lds[(0*8+h)*512 + j+1]*vv1;
        acc1 += a_lds[(1*8+h)*512 + j]*vv0 + a_lds[(1*8+h)*512 + j+1]*vv1;
        acc2 += a_lds[(2*8+h)*512 + j]*vv0 + a_lds[(2*8+h)*512 + j+1]*vv1;
        acc3 += a_lds[(3*8+h)*512 + j]*vv0 + a_lds[(3*8+h)*512 + j+1]*vv1;
    }
    o[(size_t)(bi0+0)*256 + c] = acc0;
    o[(size_t)(bi0+1)*256 + c] = acc1;
    o[(size_t)(bi0+2)*256 + c] = acc2;
    o[(size_t)(bi0+3)*256 + c] = acc3;
}

// -------- split-K combine for mlp2: out = resid + bias + sum_z part[z] --------
__global__ __launch_bounds__(256) void combine_kernel(const float* __restrict__ part,
                                                      const float* __restrict__ bias,
                                                      const float* __restrict__ resid,
                                                      float* __restrict__ out) {
    int f = blockIdx.x * 256 + threadIdx.x;   // 65536 float4s
    int e = f * 4;
    float4 r  = *(const float4*)(resid + e);
    float4 bv = *(const float4*)(bias + (e & 255));
    float4 p0 = *(const float4*)(part + e);
    float4 p1 = *(const float4*)(part + 262144 + e);
    float4 p2 = *(const float4*)(part + 524288 + e);
    float4 p3 = *(const float4*)(part + 786432 + e);
    float4 o4;
    o4.x = r.x + bv.x + p0.x + p1.x + p2.x + p3.x;
    o4.y = r.y + bv.y + p0.y + p1.y + p2.y + p3.y;
    o4.z = r.z + bv.z + p0.z + p1.z + p2.z + p3.z;
    o4.w = r.w + bv.w + p0.w + p1.w + p2.w + p3.w;
    *(float4*)(out + e) = o4;
}

extern "C" void kernel_launch(void* const* d_in, const int* in_sizes, int n_in,
                              void* d_out, int out_size, void* d_ws, size_t ws_size,
                              hipStream_t stream) {
    const float* x      = (const float*)d_in[0];
    const float* rp     = (const float*)d_in[1];
    const float* w_qkv  = (const float*)d_in[2];
    const float* w_proj = (const float*)d_in[3];
    const float* b_proj = (const float*)d_in[4];
    const float* w_rel  = (const float*)d_in[5];
    const float* b_rel  = (const float*)d_in[6];
    const float* g_reln = (const float*)d_in[7];
    const float* b_reln = (const float*)d_in[8];
    const float* g_n1   = (const float*)d_in[9];
    const float* b_n1   = (const float*)d_in[10];
    const float* g_n2   = (const float*)d_in[11];
    const float* b_n2   = (const float*)d_in[12];
    const float* w_mlp1 = (const float*)d_in[13];
    const float* b_mlp1 = (const float*)d_in[14];
    const float* w_mlp2 = (const float*)d_in[15];
    const float* b_mlp2 = (const float*)d_in[16];
    float* out = (float*)d_out;

    float* ws     = (float*)d_ws;
    float* ws_h    = ws;                    // 262144
    float* ws_qkv  = ws_h    + 262144;      // 786432
    float* ws_qk   = ws_qkv  + 786432;      // 4194304  [bi][h][j]
    float* ws_attn = ws_qk   + 4194304;     // 4194304  [bi][h][j]
    float* ws_o    = ws_attn + 4194304;     // 262144
    float* ws_x1   = ws_o    + 262144;      // 262144
    float* ws_hg   = ws_x1   + 262144;      // 1048576
    float* ws_pt   = ws_hg   + 1048576;     // 1048576

    // 1) h = LN1(x)
    ln_kernel<<<256, 256, 0, stream>>>(x, g_n1, b_n1, ws_h);
    // 2) qkv = h @ w_qkv   [1024,768]
    gemm_kernel<false,false,false,1><<<dim3(16,12,1), 256, 0, stream>>>(
        ws_h, w_qkv, nullptr, nullptr, ws_qkv, 1024, 768, 256);
    // 3) qk[bi][h][j]
    qk_kernel<<<dim3(16,8,2), 256, 0, stream>>>(ws_qkv, ws_qk);
    // 4) attn = softmax((qk + rel_bias)*scale)  — rel GEMM+GELU+LN fused, softmax fused
    rel_softmax_kernel<<<1024, 256, 0, stream>>>(rp, ws_qk, w_rel, b_rel, g_reln, b_reln, ws_attn);
    // 5) o = attn @ v
    attnv_kernel<<<256, 256, 0, stream>>>(ws_attn, ws_qkv, ws_o);
    // 6) x1 = x + o @ w_proj + b_proj
    gemm_kernel<true,false,true,1><<<dim3(16,4,1), 256, 0, stream>>>(
        ws_o, w_proj, b_proj, x, ws_x1, 1024, 256, 256);
    // 7) h2 = LN2(x1)  (reuse ws_h)
    ln_kernel<<<256, 256, 0, stream>>>(ws_x1, g_n2, b_n2, ws_h);
    // 8) hg = GELU(h2 @ w_mlp1 + b_mlp1)  [1024,1024]
    gemm_kernel<true,true,false,1><<<dim3(16,16,1), 256, 0, stream>>>(
        ws_h, w_mlp1, b_mlp1, nullptr, ws_hg, 1024, 1024, 256);
    // 9) partials = hg @ w_mlp2 (split-K=4)
    gemm_kernel<false,false,false,4><<<dim3(16,4,4), 256, 0, stream>>>(
        ws_hg, w_mlp2, nullptr, nullptr, ws_pt, 1024, 256, 1024);
    // 10) out = x1 + b_mlp2 + sum partials
    combine_kernel<<<256, 256, 0, stream>>>(ws_pt, b_mlp2, ws_x1, out);
}

// Round 4
// 333.930 us; speedup vs baseline: 1.0650x; 1.0650x over previous
//
#include <hip/hip_runtime.h>
#include <cstddef>

#define EPS_ 1e-5f
#define SCALE_ 0.1767766952966369f   // 1/sqrt(32)

__device__ __forceinline__ float gelu_f(float x) {
    return 0.5f * x * (1.0f + erff(x * 0.7071067811865476f));
}

// -------- LayerNorm over C=256, one wave per row --------
__global__ __launch_bounds__(256) void ln_kernel(const float* __restrict__ x,
                                                 const float* __restrict__ g,
                                                 const float* __restrict__ b,
                                                 float* __restrict__ out) {
    int wid = threadIdx.x >> 6, lane = threadIdx.x & 63;
    int row = blockIdx.x * 4 + wid;
    const float4 xv = *(const float4*)(x + (size_t)row * 256 + lane * 4);
    float s  = xv.x + xv.y + xv.z + xv.w;
    float sq = xv.x*xv.x + xv.y*xv.y + xv.z*xv.z + xv.w*xv.w;
#pragma unroll
    for (int m = 1; m < 64; m <<= 1) { s += __shfl_xor(s, m); sq += __shfl_xor(sq, m); }
    float mean = s * (1.0f/256.0f);
    float var  = sq * (1.0f/256.0f) - mean*mean;
    float rstd = rsqrtf(var + EPS_);
    float4 gv = *(const float4*)(g + lane*4);
    float4 bv = *(const float4*)(b + lane*4);
    float4 o;
    o.x = (xv.x-mean)*rstd*gv.x + bv.x;
    o.y = (xv.y-mean)*rstd*gv.y + bv.y;
    o.z = (xv.z-mean)*rstd*gv.z + bv.z;
    o.w = (xv.w-mean)*rstd*gv.w + bv.w;
    *(float4*)(out + (size_t)row * 256 + lane * 4) = o;
}

// -------- Generic tiled f32 GEMM: C = A[M,K] @ B[K,N] (+bias)(gelu)(+resid) --------
template<bool BIAS, bool GACT, bool RESID, int KSPLIT>
__global__ __launch_bounds__(256) void gemm_kernel(
    const float* __restrict__ A, const float* __restrict__ Bm,
    const float* __restrict__ bias, const float* __restrict__ resid,
    float* __restrict__ Cout, int M, int N, int K) {
    __shared__ float As[16][68];
    __shared__ float Bs[16][64];
    int t = threadIdx.x;
    int bm = blockIdx.x, bn = blockIdx.y, kz = blockIdx.z;
    int kchunk = K / KSPLIT;
    int k0 = kz * kchunk;
    int tm = t >> 4, tn = t & 15;
    int la_m = t >> 2, la_k = (t & 3) << 2;
    int lb_k = t >> 4, lb_n = (t & 15) << 2;
    float acc[4][4] = {};
    const float* Aptr = A  + (size_t)(bm*64 + la_m) * K + k0 + la_k;
    const float* Bptr = Bm + (size_t)(k0 + lb_k) * N + bn*64 + lb_n;
    for (int kk = 0; kk < kchunk; kk += 16) {
        float4 a4 = *(const float4*)(Aptr + kk);
        float4 b4 = *(const float4*)(Bptr + (size_t)kk * N);
        __syncthreads();
        As[la_k+0][la_m] = a4.x;
        As[la_k+1][la_m] = a4.y;
        As[la_k+2][la_m] = a4.z;
        As[la_k+3][la_m] = a4.w;
        *(float4*)(&Bs[lb_k][lb_n]) = b4;
        __syncthreads();
#pragma unroll
        for (int k = 0; k < 16; ++k) {
            float4 av = *(const float4*)(&As[k][tm<<2]);
            float4 bv = *(const float4*)(&Bs[k][tn<<2]);
            acc[0][0] += av.x*bv.x; acc[0][1] += av.x*bv.y; acc[0][2] += av.x*bv.z; acc[0][3] += av.x*bv.w;
            acc[1][0] += av.y*bv.x; acc[1][1] += av.y*bv.y; acc[1][2] += av.y*bv.z; acc[1][3] += av.y*bv.w;
            acc[2][0] += av.z*bv.x; acc[2][1] += av.z*bv.y; acc[2][2] += av.z*bv.z; acc[2][3] += av.z*bv.w;
            acc[3][0] += av.w*bv.x; acc[3][1] += av.w*bv.y; acc[3][2] += av.w*bv.z; acc[3][3] += av.w*bv.w;
        }
    }
    int row0 = bm*64 + tm*4, col0 = bn*64 + tn*4;
    float4 bv4 = make_float4(0.f,0.f,0.f,0.f);
    if (BIAS) bv4 = *(const float4*)(bias + col0);
#pragma unroll
    for (int i2 = 0; i2 < 4; ++i2) {
        float4 r;
        r.x = acc[i2][0]; r.y = acc[i2][1]; r.z = acc[i2][2]; r.w = acc[i2][3];
        if (BIAS) { r.x += bv4.x; r.y += bv4.y; r.z += bv4.z; r.w += bv4.w; }
        if (GACT) { r.x = gelu_f(r.x); r.y = gelu_f(r.y); r.z = gelu_f(r.z); r.w = gelu_f(r.w); }
        if (RESID) {
            float4 rv = *(const float4*)(resid + (size_t)(row0+i2)*N + col0);
            r.x += rv.x; r.y += rv.y; r.z += rv.z; r.w += rv.w;
        }
        float* dst = Cout + (KSPLIT > 1 ? (size_t)kz * M * N : (size_t)0) + (size_t)(row0+i2)*N + col0;
        *(float4*)dst = r;
    }
}

// -------- qk[bi][j][h] = q_i^h . k_j^h ; block = (i-tile 32, h, b), k staged in LDS --------
// Output TRANSPOSED to [bi][j][h] so the rel kernel reads it coalesced.
__global__ __launch_bounds__(256) void qk_kernel(const float* __restrict__ qkv,
                                                 float* __restrict__ qk) {
    __shared__ float k_lds[512*32];   // 64 KB
    int t = threadIdx.x;
    int it = blockIdx.x;              // 0..15
    int h  = blockIdx.y;              // 0..7
    int b  = blockIdx.z;              // 0..1
    const float* base = qkv + (size_t)b * 393216;
    // stage k[b, :, h*32:(h+1)*32]
#pragma unroll
    for (int r = 0; r < 16; ++r) {
        int idx = r*256 + t;
        int row = idx >> 3, c4 = idx & 7;
        float4 kv = *(const float4*)(base + (size_t)row*768 + 256 + h*32 + c4*4);
        *(float4*)(k_lds + row*32 + c4*4) = kv;
    }
    __syncthreads();
    int ir = t & 31, jg = t >> 5;     // thread: row i0+ir, j-slice jg*64..+63
    int i = it*32 + ir;
    // q row into registers (8 float4 = 32 VGPR)
    float4 q[8];
    const float* qp = base + (size_t)i*768 + h*32;
#pragma unroll
    for (int c4 = 0; c4 < 8; ++c4) q[c4] = *(const float4*)(qp + c4*4);
    float* outp = qk + ((size_t)(b*512 + i))*4096 + (size_t)(jg*64)*8 + h;
    for (int jj = 0; jj < 64; ++jj) {
        const float* kp = k_lds + (size_t)(jg*64 + jj)*32;
        float acc = 0.f;
#pragma unroll
        for (int c4 = 0; c4 < 8; ++c4) {
            float4 kv = *(const float4*)(kp + c4*4);
            acc += q[c4].x*kv.x + q[c4].y*kv.y + q[c4].z*kv.z + q[c4].w*kv.w;
        }
        outp[(size_t)jj*8] = acc;
    }
}

// -------- Fused rel-bias + logits + softmax. Block = (b,i); wave owns j; lane owns 4 channels. --------
// attn[bi][h][j] = softmax_j( (qk[bi][j][h] + LN(GELU(rp[bi,j,:]@w_rel + b_rel))[h]) * scale )
#define LGS 520   // logit LDS row stride (pad vs 512 -> conflict-free writes)
__global__ __launch_bounds__(256) void rel_softmax_kernel(
    const float* __restrict__ rp, const float* __restrict__ qk,
    const float* __restrict__ w_rel, const float* __restrict__ b_rel,
    const float* __restrict__ g_reln, const float* __restrict__ b_reln,
    float* __restrict__ attn) {
    __shared__ float lg_lds[8*LGS];   // 16.6 KB
    int t = threadIdx.x;
    int bi = blockIdx.x;              // b*512 + i
    int wid = t >> 6, lane = t & 63;
    int b0 = lane & 1, b1 = (lane >> 1) & 1, b2 = (lane >> 2) & 1;
    int hl = 4*b0 + 2*b1 + b2;        // head this lane ends up holding after the fold
    // preload w_rel rows c=4*lane..+3 (each row = 8 floats) into 32 VGPRs
    float w[4][8];
    {
        const float* wr = w_rel + (size_t)lane * 32;
#pragma unroll
        for (int u = 0; u < 4; ++u) {
            float4 w0 = *(const float4*)(wr + u*8);
            float4 w1 = *(const float4*)(wr + u*8 + 4);
            w[u][0]=w0.x; w[u][1]=w0.y; w[u][2]=w0.z; w[u][3]=w0.w;
            w[u][4]=w1.x; w[u][5]=w1.y; w[u][6]=w1.z; w[u][7]=w1.w;
        }
    }
    float brel = b_rel[hl], grn = g_reln[hl], brn = b_reln[hl];
    const float* rpb = rp + (size_t)bi * 512 * 256;
    const float* qkb = qk + (size_t)bi * 4096;
    int j0 = wid * 128;
    for (int jj = 0; jj < 128; ++jj) {
        int j = j0 + jj;
        float4 r4 = *(const float4*)(rpb + (size_t)j * 256 + lane * 4);
        float qkj = qkb[(size_t)j * 8 + hl];   // coalesced: 8 consecutive dwords per group
        // 8 head partials over this lane's 4 c's
        float p0 = r4.x*w[0][0] + r4.y*w[1][0] + r4.z*w[2][0] + r4.w*w[3][0];
        float p1 = r4.x*w[0][1] + r4.y*w[1][1] + r4.z*w[2][1] + r4.w*w[3][1];
        float p2 = r4.x*w[0][2] + r4.y*w[1][2] + r4.z*w[2][2] + r4.w*w[3][2];
        float p3 = r4.x*w[0][3] + r4.y*w[1][3] + r4.z*w[2][3] + r4.w*w[3][3];
        float p4 = r4.x*w[0][4] + r4.y*w[1][4] + r4.z*w[2][4] + r4.w*w[3][4];
        float p5 = r4.x*w[0][5] + r4.y*w[1][5] + r4.z*w[2][5] + r4.w*w[3][5];
        float p6 = r4.x*w[0][6] + r4.y*w[1][6] + r4.z*w[2][6] + r4.w*w[3][6];
        float p7 = r4.x*w[0][7] + r4.y*w[1][7] + r4.z*w[2][7] + r4.w*w[3][7];
        // log-fold reduce of 8 rel partials across 64 lanes (lane ends with head hl)
        float f0 = (b0 ? p4 : p0) + __shfl_xor(b0 ? p0 : p4, 1);
        float f1 = (b0 ? p5 : p1) + __shfl_xor(b0 ? p1 : p5, 1);
        float f2 = (b0 ? p6 : p2) + __shfl_xor(b0 ? p2 : p6, 1);
        float f3 = (b0 ? p7 : p3) + __shfl_xor(b0 ? p3 : p7, 1);
        float e0 = (b1 ? f2 : f0) + __shfl_xor(b1 ? f0 : f2, 2);
        float e1 = (b1 ? f3 : f1) + __shfl_xor(b1 ? f1 : f3, 2);
        float S  = (b2 ? e1 : e0) + __shfl_xor(b2 ? e0 : e1, 4);
        S += __shfl_xor(S, 8); S += __shfl_xor(S, 16); S += __shfl_xor(S, 32);
        // GELU(exact) then LayerNorm over the 8 heads (held by the 8 lanes of each group)
        float val = S + brel;
        float gv = 0.5f * val * (1.0f + erff(val * 0.7071067811865476f));
        float sm = gv, sq = gv*gv;
        sm += __shfl_xor(sm, 1); sq += __shfl_xor(sq, 1);
        sm += __shfl_xor(sm, 2); sq += __shfl_xor(sq, 2);
        sm += __shfl_xor(sm, 4); sq += __shfl_xor(sq, 4);
        float mean = sm * 0.125f;
        float var  = sq * 0.125f - mean*mean;
        float reln = (gv - mean) * rsqrtf(var + EPS_) * grn + brn;
        if (lane < 8) lg_lds[hl*LGS + j] = (qkj + reln) * SCALE_;
    }
    __syncthreads();
    // fused softmax: half-wave (32 lanes) per head row
    {
        int h = wid*2 + (lane >> 5);
        int sub = lane & 31;
        float* row = lg_lds + h*LGS + sub*16;
        float v[16];
        *(float4*)(v +  0) = *(float4*)(row + 0);
        *(float4*)(v +  4) = *(float4*)(row + 4);
        *(float4*)(v +  8) = *(float4*)(row + 8);
        *(float4*)(v + 12) = *(float4*)(row + 12);
        float mx = v[0];
#pragma unroll
        for (int e = 1; e < 16; ++e) mx = fmaxf(mx, v[e]);
#pragma unroll
        for (int m = 1; m < 32; m <<= 1) mx = fmaxf(mx, __shfl_xor(mx, m));
        float s = 0.f;
#pragma unroll
        for (int e = 0; e < 16; ++e) { v[e] = expf(v[e] - mx); s += v[e]; }
#pragma unroll
        for (int m = 1; m < 32; m <<= 1) s += __shfl_xor(s, m);
        float inv = 1.0f / s;
#pragma unroll
        for (int e = 0; e < 16; ++e) v[e] *= inv;
        float* dst = attn + (size_t)bi*4096 + h*512 + sub*16;
        *(float4*)(dst +  0) = *(float4*)(v +  0);
        *(float4*)(dst +  4) = *(float4*)(v +  4);
        *(float4*)(dst +  8) = *(float4*)(v +  8);
        *(float4*)(dst + 12) = *(float4*)(v + 12);
    }
}

// -------- o = attn @ v. Block = 4 bi rows (attn in LDS); thread owns out column c. --------
__global__ __launch_bounds__(256) void attnv_kernel(const float* __restrict__ attn,
                                                    const float* __restrict__ qkv,
                                                    float* __restrict__ o) {
    __shared__ float a_lds[4*8*512];  // 64 KB
    int t = threadIdx.x;
    int bi0 = blockIdx.x * 4;
    int b = bi0 >> 9;
    const float4* asrc = (const float4*)(attn + (size_t)bi0*4096);
    float4* adst = (float4*)a_lds;
#pragma unroll
    for (int r = 0; r < 16; ++r) adst[r*256 + t] = asrc[r*256 + t];
    __syncthreads();
    int c = t, h = c >> 5;
    const float* vcol = qkv + (size_t)b*393216 + 512 + c;
    float acc0 = 0.f, acc1 = 0.f, acc2 = 0.f, acc3 = 0.f;
    for (int j = 0; j < 512; j += 2) {
        float vv0 = vcol[(size_t)j*768];
        float vv1 = vcol[(size_t)(j+1)*768];
        acc0 += a_lds[(0*8+h)*512 + j]*vv0 + a_lds[(0*8+h)*512 + j+1]*vv1;
        acc1 += a_lds[(1*8+h)*512 + j]*vv0 + a_lds[(1*8+h)*512 + j+1]*vv1;
        acc2 += a_lds[(2*8+h)*512 + j]*vv0 + a_lds[(2*8+h)*512 + j+1]*vv1;
        acc3 += a_lds[(3*8+h)*512 + j]*vv0 + a_lds[(3*8+h)*512 + j+1]*vv1;
    }
    o[(size_t)(bi0+0)*256 + c] = acc0;
    o[(size_t)(bi0+1)*256 + c] = acc1;
    o[(size_t)(bi0+2)*256 + c] = acc2;
    o[(size_t)(bi0+3)*256 + c] = acc3;
}

// -------- split-K combine for mlp2: out = resid + bias + sum_z part[z] --------
__global__ __launch_bounds__(256) void combine_kernel(const float* __restrict__ part,
                                                      const float* __restrict__ bias,
                                                      const float* __restrict__ resid,
                                                      float* __restrict__ out) {
    int f = blockIdx.x * 256 + threadIdx.x;   // 65536 float4s
    int e = f * 4;
    float4 r  = *(const float4*)(resid + e);
    float4 bv = *(const float4*)(bias + (e & 255));
    float4 p0 = *(const float4*)(part + e);
    float4 p1 = *(const float4*)(part + 262144 + e);
    float4 p2 = *(const float4*)(part + 524288 + e);
    float4 p3 = *(const float4*)(part + 786432 + e);
    float4 o4;
    o4.x = r.x + bv.x + p0.x + p1.x + p2.x + p3.x;
    o4.y = r.y + bv.y + p0.y + p1.y + p2.y + p3.y;
    o4.z = r.z + bv.z + p0.z + p1.z + p2.z + p3.z;
    o4.w = r.w + bv.w + p0.w + p1.w + p2.w + p3.w;
    *(float4*)(out + e) = o4;
}

extern "C" void kernel_launch(void* const* d_in, const int* in_sizes, int n_in,
                              void* d_out, int out_size, void* d_ws, size_t ws_size,
                              hipStream_t stream) {
    const float* x      = (const float*)d_in[0];
    const float* rp     = (const float*)d_in[1];
    const float* w_qkv  = (const float*)d_in[2];
    const float* w_proj = (const float*)d_in[3];
    const float* b_proj = (const float*)d_in[4];
    const float* w_rel  = (const float*)d_in[5];
    const float* b_rel  = (const float*)d_in[6];
    const float* g_reln = (const float*)d_in[7];
    const float* b_reln = (const float*)d_in[8];
    const float* g_n1   = (const float*)d_in[9];
    const float* b_n1   = (const float*)d_in[10];
    const float* g_n2   = (const float*)d_in[11];
    const float* b_n2   = (const float*)d_in[12];
    const float* w_mlp1 = (const float*)d_in[13];
    const float* b_mlp1 = (const float*)d_in[14];
    const float* w_mlp2 = (const float*)d_in[15];
    const float* b_mlp2 = (const float*)d_in[16];
    float* out = (float*)d_out;

    float* ws     = (float*)d_ws;
    float* ws_h    = ws;                    // 262144
    float* ws_qkv  = ws_h    + 262144;      // 786432
    float* ws_qk   = ws_qkv  + 786432;      // 4194304  [bi][j][h]
    float* ws_attn = ws_qk   + 4194304;     // 4194304  [bi][h][j]
    float* ws_o    = ws_attn + 4194304;     // 262144
    float* ws_x1   = ws_o    + 262144;      // 262144
    float* ws_hg   = ws_x1   + 262144;      // 1048576
    float* ws_pt   = ws_hg   + 1048576;     // 1048576

    // 1) h = LN1(x)
    ln_kernel<<<256, 256, 0, stream>>>(x, g_n1, b_n1, ws_h);
    // 2) qkv = h @ w_qkv   [1024,768]
    gemm_kernel<false,false,false,1><<<dim3(16,12,1), 256, 0, stream>>>(
        ws_h, w_qkv, nullptr, nullptr, ws_qkv, 1024, 768, 256);
    // 3) qk[bi][j][h]
    qk_kernel<<<dim3(16,8,2), 256, 0, stream>>>(ws_qkv, ws_qk);
    // 4) attn = softmax((qk + rel_bias)*scale)  — rel GEMM+GELU+LN fused, softmax fused
    rel_softmax_kernel<<<1024, 256, 0, stream>>>(rp, ws_qk, w_rel, b_rel, g_reln, b_reln, ws_attn);
    // 5) o = attn @ v
    attnv_kernel<<<256, 256, 0, stream>>>(ws_attn, ws_qkv, ws_o);
    // 6) x1 = x + o @ w_proj + b_proj
    gemm_kernel<true,false,true,1><<<dim3(16,4,1), 256, 0, stream>>>(
        ws_o, w_proj, b_proj, x, ws_x1, 1024, 256, 256);
    // 7) h2 = LN2(x1)  (reuse ws_h)
    ln_kernel<<<256, 256, 0, stream>>>(ws_x1, g_n2, b_n2, ws_h);
    // 8) hg = GELU(h2 @ w_mlp1 + b_mlp1)  [1024,1024]
    gemm_kernel<true,true,false,1><<<dim3(16,16,1), 256, 0, stream>>>(
        ws_h, w_mlp1, b_mlp1, nullptr, ws_hg, 1024, 1024, 256);
    // 9) partials = hg @ w_mlp2 (split-K=4)
    gemm_kernel<false,false,false,4><<<dim3(16,4,4), 256, 0, stream>>>(
        ws_hg, w_mlp2, nullptr, nullptr, ws_pt, 1024, 256, 1024);
    // 10) out = x1 + b_mlp2 + sum partials
    combine_kernel<<<256, 256, 0, stream>>>(ws_pt, b_mlp2, ws_x1, out);
}

// Round 5
// 273.532 us; speedup vs baseline: 1.3001x; 1.2208x over previous
//
#include <hip/hip_runtime.h>
#include <cstddef>

#define EPS_ 1e-5f
#define SCALE_ 0.1767766952966369f   // 1/sqrt(32)

typedef short bf16x8_t __attribute__((ext_vector_type(8)));   // 8 bf16 in 4 VGPRs
typedef float f32x4_t  __attribute__((ext_vector_type(4)));

__device__ __forceinline__ float gelu_f(float x) {
    return 0.5f * x * (1.0f + erff(x * 0.7071067811865476f));
}
__device__ __forceinline__ unsigned short f2bf(float f) {
    unsigned u = __builtin_bit_cast(unsigned, f);
    u += 0x7FFFu + ((u >> 16) & 1u);           // RNE
    return (unsigned short)(u >> 16);
}

// -------- LayerNorm over C=256, one wave per row, bf16 output --------
__global__ __launch_bounds__(256) void ln_kernel(const float* __restrict__ x,
                                                 const float* __restrict__ g,
                                                 const float* __restrict__ b,
                                                 unsigned short* __restrict__ out) {
    int wid = threadIdx.x >> 6, lane = threadIdx.x & 63;
    int row = blockIdx.x * 4 + wid;
    const float4 xv = *(const float4*)(x + (size_t)row * 256 + lane * 4);
    float s  = xv.x + xv.y + xv.z + xv.w;
    float sq = xv.x*xv.x + xv.y*xv.y + xv.z*xv.z + xv.w*xv.w;
#pragma unroll
    for (int m = 1; m < 64; m <<= 1) { s += __shfl_xor(s, m); sq += __shfl_xor(sq, m); }
    float mean = s * (1.0f/256.0f);
    float var  = sq * (1.0f/256.0f) - mean*mean;
    float rstd = rsqrtf(var + EPS_);
    float4 gv = *(const float4*)(g + lane*4);
    float4 bv = *(const float4*)(b + lane*4);
    ushort4 o;
    o.x = f2bf((xv.x-mean)*rstd*gv.x + bv.x);
    o.y = f2bf((xv.y-mean)*rstd*gv.y + bv.y);
    o.z = f2bf((xv.z-mean)*rstd*gv.z + bv.z);
    o.w = f2bf((xv.w-mean)*rstd*gv.w + bv.w);
    *(ushort4*)(out + (size_t)row * 256 + lane * 4) = o;
}

// -------- transpose + convert the 4 weight matrices: W[K][N] f32 -> WT[N][K] bf16 --------
__global__ __launch_bounds__(256) void convw_kernel(
    const float* __restrict__ w_qkv,  unsigned short* __restrict__ wqkvT,
    const float* __restrict__ w_proj, unsigned short* __restrict__ wprojT,
    const float* __restrict__ w_mlp1, unsigned short* __restrict__ wmlp1T,
    const float* __restrict__ w_mlp2, unsigned short* __restrict__ wmlp2T) {
    __shared__ float tile[32][33];
    int bid = blockIdx.x, t = threadIdx.x;
    const float* W; unsigned short* WT; int K, N, tt;
    if (bid < 192)      { W = w_qkv;  WT = wqkvT;  K = 256;  N = 768;  tt = bid; }
    else if (bid < 256) { W = w_proj; WT = wprojT; K = 256;  N = 256;  tt = bid - 192; }
    else if (bid < 512) { W = w_mlp1; WT = wmlp1T; K = 256;  N = 1024; tt = bid - 256; }
    else                { W = w_mlp2; WT = wmlp2T; K = 1024; N = 256;  tt = bid - 512; }
    int ntn = N >> 5;
    int kt = tt / ntn, nt = tt % ntn;
    int k0 = kt * 32, n0 = nt * 32;
    {
        int kr = t >> 3, cg = (t & 7) * 4;
        float4 v = *(const float4*)(W + (size_t)(k0 + kr) * N + n0 + cg);
        tile[kr][cg+0] = v.x; tile[kr][cg+1] = v.y; tile[kr][cg+2] = v.z; tile[kr][cg+3] = v.w;
    }
    __syncthreads();
    {
        int nr = t >> 3, kg = (t & 7) * 4;
        ushort4 o;
        o.x = f2bf(tile[kg+0][nr]); o.y = f2bf(tile[kg+1][nr]);
        o.z = f2bf(tile[kg+2][nr]); o.w = f2bf(tile[kg+3][nr]);
        *(ushort4*)(WT + (size_t)(n0 + nr) * K + k0 + kg) = o;
    }
}

// -------- bf16 MFMA GEMM: C[M,N] = A[M,K](bf16) @ BT[N,K]^T(bf16) (+bias)(gelu)(+resid) --------
// 64x64 tile, 4 waves in 2x2, each wave 32x32 via 2x2 mfma_f32_16x16x32_bf16 tiles.
template<bool BIAS, bool GACT, bool RESID, bool BF16OUT, int KSPLIT>
__global__ __launch_bounds__(256) void mgemm_kernel(
    const unsigned short* __restrict__ A, const unsigned short* __restrict__ BT,
    const float* __restrict__ bias, const float* __restrict__ resid,
    void* __restrict__ Cout, int M, int N, int K) {
    __shared__ unsigned short Al[64][40];
    __shared__ unsigned short Bl[64][40];
    int t = threadIdx.x;
    int bm = blockIdx.x, bn = blockIdx.y, kz = blockIdx.z;
    int kchunk = K / KSPLIT;
    int srow = t >> 2, skk = (t & 3) * 8;
    const unsigned short* Ap = A  + (size_t)(bm*64 + srow) * K + kz*kchunk + skk;
    const unsigned short* Bp = BT + (size_t)(bn*64 + srow) * K + kz*kchunk + skk;
    int lane = t & 63, w = t >> 6, wr = w >> 1, wc = w & 1;
    int fr = lane & 15, fg = lane >> 4;
    f32x4_t a00 = {0.f,0.f,0.f,0.f}, a01 = {0.f,0.f,0.f,0.f};
    f32x4_t a10 = {0.f,0.f,0.f,0.f}, a11 = {0.f,0.f,0.f,0.f};
    for (int kk = 0; kk < kchunk; kk += 32) {
        uint4 av = *(const uint4*)(Ap + kk);
        uint4 bv = *(const uint4*)(Bp + kk);
        __syncthreads();
        *(uint4*)&Al[srow][skk] = av;
        *(uint4*)&Bl[srow][skk] = bv;
        __syncthreads();
        bf16x8_t fa0 = *(const bf16x8_t*)&Al[wr*32      + fr][fg*8];
        bf16x8_t fa1 = *(const bf16x8_t*)&Al[wr*32 + 16 + fr][fg*8];
        bf16x8_t fb0 = *(const bf16x8_t*)&Bl[wc*32      + fr][fg*8];
        bf16x8_t fb1 = *(const bf16x8_t*)&Bl[wc*32 + 16 + fr][fg*8];
        a00 = __builtin_amdgcn_mfma_f32_16x16x32_bf16(fa0, fb0, a00, 0, 0, 0);
        a01 = __builtin_amdgcn_mfma_f32_16x16x32_bf16(fa0, fb1, a01, 0, 0, 0);
        a10 = __builtin_amdgcn_mfma_f32_16x16x32_bf16(fa1, fb0, a10, 0, 0, 0);
        a11 = __builtin_amdgcn_mfma_f32_16x16x32_bf16(fa1, fb1, a11, 0, 0, 0);
    }
    float* Cf = (float*)Cout + (KSPLIT > 1 ? (size_t)kz * M * N : (size_t)0);
    unsigned short* Cb = (unsigned short*)Cout;
    auto emit = [&](f32x4_t acc, int mi, int ni) {
        int Ro = bm*64 + wr*32 + mi*16 + fg*4;
        int Co = bn*64 + wc*32 + ni*16 + fr;
        float bval = BIAS ? bias[Co] : 0.f;
#pragma unroll
        for (int e = 0; e < 4; ++e) {
            int r = Ro + e;
            float v = acc[e];
            if (BIAS)  v += bval;
            if (GACT)  v = gelu_f(v);
            if (RESID) v += resid[(size_t)r * N + Co];
            if (BF16OUT) Cb[(size_t)r * N + Co] = f2bf(v);
            else         Cf[(size_t)r * N + Co] = v;
        }
    };
    emit(a00, 0, 0); emit(a01, 0, 1); emit(a10, 1, 0); emit(a11, 1, 1);
}

// -------- qk[bi][h][j] = q_i^h . k_j^h ; block = (i-tile 32, h, b), k staged in LDS --------
__global__ __launch_bounds__(256) void qk_kernel(const float* __restrict__ qkv,
                                                 float* __restrict__ qk) {
    __shared__ float k_lds[512*32];   // 64 KB
    int t = threadIdx.x;
    int it = blockIdx.x;              // 0..15
    int h  = blockIdx.y;              // 0..7
    int b  = blockIdx.z;              // 0..1
    const float* base = qkv + (size_t)b * 393216;
#pragma unroll
    for (int r = 0; r < 16; ++r) {
        int idx = r*256 + t;
        int row = idx >> 3, c4 = idx & 7;
        float4 kv = *(const float4*)(base + (size_t)row*768 + 256 + h*32 + c4*4);
        *(float4*)(k_lds + row*32 + c4*4) = kv;
    }
    __syncthreads();
    int ir = t & 31, jg = t >> 5;     // thread: row it*32+ir, j-slice jg*64..+63
    int i = it*32 + ir;
    float4 q[8];
    const float* qp = base + (size_t)i*768 + h*32;
#pragma unroll
    for (int c4 = 0; c4 < 8; ++c4) q[c4] = *(const float4*)(qp + c4*4);
    float* outp = qk + (((size_t)(b*512 + i))*8 + h)*512 + jg*64;
    for (int jj = 0; jj < 64; jj += 4) {
        float a4[4];
#pragma unroll
        for (int u = 0; u < 4; ++u) {
            const float* kp = k_lds + (size_t)(jg*64 + jj + u)*32;
            float acc = 0.f;
#pragma unroll
            for (int c4 = 0; c4 < 8; ++c4) {
                float4 kv = *(const float4*)(kp + c4*4);
                acc += q[c4].x*kv.x + q[c4].y*kv.y + q[c4].z*kv.z + q[c4].w*kv.w;
            }
            a4[u] = acc;
        }
        *(float4*)(outp + jj) = make_float4(a4[0], a4[1], a4[2], a4[3]);
    }
}

// -------- Fused rel-bias + softmax. Block = (b,i); wave owns 128 j; lane owns 4 channels. --------
// attn[bi][h][j] = softmax_j( (qk[bi][h][j] + LN(GELU(rp[bi,j,:]@w_rel + b_rel))[h]) * scale )
#define LGS 520   // logit LDS row stride (pad vs 512 -> conflict-free)
__global__ __launch_bounds__(256) void rel_softmax_kernel(
    const float* __restrict__ rp, const float* __restrict__ qk,
    const float* __restrict__ w_rel, const float* __restrict__ b_rel,
    const float* __restrict__ g_reln, const float* __restrict__ b_reln,
    float* __restrict__ attn) {
    __shared__ float lg_lds[8*LGS];   // 16.6 KB of rel-bias values
    int t = threadIdx.x;
    int bi = blockIdx.x;              // b*512 + i
    int wid = t >> 6, lane = t & 63;
    int b0 = lane & 1, b1 = (lane >> 1) & 1, b2 = (lane >> 2) & 1;
    int hl = 4*b0 + 2*b1 + b2;        // head this lane holds after the fold
    float w[4][8];
    {
        const float* wr = w_rel + (size_t)lane * 32;
#pragma unroll
        for (int u = 0; u < 4; ++u) {
            float4 w0 = *(const float4*)(wr + u*8);
            float4 w1 = *(const float4*)(wr + u*8 + 4);
            w[u][0]=w0.x; w[u][1]=w0.y; w[u][2]=w0.z; w[u][3]=w0.w;
            w[u][4]=w1.x; w[u][5]=w1.y; w[u][6]=w1.z; w[u][7]=w1.w;
        }
    }
    float brel = b_rel[hl], grn = g_reln[hl], brn = b_reln[hl];
    const float* rpb = rp + (size_t)bi * 512 * 256;
    int j0 = wid * 128;
    for (int jj = 0; jj < 128; ++jj) {
        int j = j0 + jj;
        float4 r4 = *(const float4*)(rpb + (size_t)j * 256 + lane * 4);
        float p0 = r4.x*w[0][0] + r4.y*w[1][0] + r4.z*w[2][0] + r4.w*w[3][0];
        float p1 = r4.x*w[0][1] + r4.y*w[1][1] + r4.z*w[2][1] + r4.w*w[3][1];
        float p2 = r4.x*w[0][2] + r4.y*w[1][2] + r4.z*w[2][2] + r4.w*w[3][2];
        float p3 = r4.x*w[0][3] + r4.y*w[1][3] + r4.z*w[2][3] + r4.w*w[3][3];
        float p4 = r4.x*w[0][4] + r4.y*w[1][4] + r4.z*w[2][4] + r4.w*w[3][4];
        float p5 = r4.x*w[0][5] + r4.y*w[1][5] + r4.z*w[2][5] + r4.w*w[3][5];
        float p6 = r4.x*w[0][6] + r4.y*w[1][6] + r4.z*w[2][6] + r4.w*w[3][6];
        float p7 = r4.x*w[0][7] + r4.y*w[1][7] + r4.z*w[2][7] + r4.w*w[3][7];
        float f0 = (b0 ? p4 : p0) + __shfl_xor(b0 ? p0 : p4, 1);
        float f1 = (b0 ? p5 : p1) + __shfl_xor(b0 ? p1 : p5, 1);
        float f2 = (b0 ? p6 : p2) + __shfl_xor(b0 ? p2 : p6, 1);
        float f3 = (b0 ? p7 : p3) + __shfl_xor(b0 ? p3 : p7, 1);
        float e0 = (b1 ? f2 : f0) + __shfl_xor(b1 ? f0 : f2, 2);
        float e1 = (b1 ? f3 : f1) + __shfl_xor(b1 ? f1 : f3, 2);
        float S  = (b2 ? e1 : e0) + __shfl_xor(b2 ? e0 : e1, 4);
        S += __shfl_xor(S, 8); S += __shfl_xor(S, 16); S += __shfl_xor(S, 32);
        float val = S + brel;
        float gv = 0.5f * val * (1.0f + erff(val * 0.7071067811865476f));
        float sm = gv, sq = gv*gv;
        sm += __shfl_xor(sm, 1); sq += __shfl_xor(sq, 1);
        sm += __shfl_xor(sm, 2); sq += __shfl_xor(sq, 2);
        sm += __shfl_xor(sm, 4); sq += __shfl_xor(sq, 4);
        float mean = sm * 0.125f;
        float var  = sq * 0.125f - mean*mean;
        float reln = (gv - mean) * rsqrtf(var + EPS_) * grn + brn;
        if (lane < 8) lg_lds[hl*LGS + j] = reln;
    }
    __syncthreads();
    // fused softmax: half-wave (32 lanes) per head row; qk row read coalesced here
    {
        int h = wid*2 + (lane >> 5);
        int sub = lane & 31;
        float* row = lg_lds + h*LGS + sub*16;
        const float* qrow = qk + ((size_t)bi*8 + h)*512 + sub*16;
        float v[16];
        float4 q0 = *(const float4*)(qrow + 0),  q1 = *(const float4*)(qrow + 4);
        float4 q2 = *(const float4*)(qrow + 8),  q3 = *(const float4*)(qrow + 12);
        float4 r0 = *(float4*)(row + 0),  r1 = *(float4*)(row + 4);
        float4 r2 = *(float4*)(row + 8),  r3 = *(float4*)(row + 12);
        v[0]=(q0.x+r0.x)*SCALE_; v[1]=(q0.y+r0.y)*SCALE_; v[2]=(q0.z+r0.z)*SCALE_; v[3]=(q0.w+r0.w)*SCALE_;
        v[4]=(q1.x+r1.x)*SCALE_; v[5]=(q1.y+r1.y)*SCALE_; v[6]=(q1.z+r1.z)*SCALE_; v[7]=(q1.w+r1.w)*SCALE_;
        v[8]=(q2.x+r2.x)*SCALE_; v[9]=(q2.y+r2.y)*SCALE_; v[10]=(q2.z+r2.z)*SCALE_; v[11]=(q2.w+r2.w)*SCALE_;
        v[12]=(q3.x+r3.x)*SCALE_; v[13]=(q3.y+r3.y)*SCALE_; v[14]=(q3.z+r3.z)*SCALE_; v[15]=(q3.w+r3.w)*SCALE_;
        float mx = v[0];
#pragma unroll
        for (int e = 1; e < 16; ++e) mx = fmaxf(mx, v[e]);
#pragma unroll
        for (int m = 1; m < 32; m <<= 1) mx = fmaxf(mx, __shfl_xor(mx, m));
        float s = 0.f;
#pragma unroll
        for (int e = 0; e < 16; ++e) { v[e] = expf(v[e] - mx); s += v[e]; }
#pragma unroll
        for (int m = 1; m < 32; m <<= 1) s += __shfl_xor(s, m);
        float inv = 1.0f / s;
#pragma unroll
        for (int e = 0; e < 16; ++e) v[e] *= inv;
        float* dst = attn + (size_t)bi*4096 + h*512 + sub*16;
        *(float4*)(dst +  0) = *(float4*)(v +  0);
        *(float4*)(dst +  4) = *(float4*)(v +  4);
        *(float4*)(dst +  8) = *(float4*)(v +  8);
        *(float4*)(dst + 12) = *(float4*)(v + 12);
    }
}

// -------- o = attn @ v (bf16 out). Block = 4 bi rows (attn in LDS); thread owns column c. --------
__global__ __launch_bounds__(256) void attnv_kernel(const float* __restrict__ attn,
                                                    const float* __restrict__ qkv,
                                                    unsigned short* __restrict__ o) {
    __shared__ float a_lds[4*8*512];  // 64 KB
    int t = threadIdx.x;
    int bi0 = blockIdx.x * 4;
    int b = bi0 >> 9;
    const float4* asrc = (const float4*)(attn + (size_t)bi0*4096);
    float4* adst = (float4*)a_lds;
#pragma unroll
    for (int r = 0; r < 16; ++r) adst[r*256 + t] = asrc[r*256 + t];
    __syncthreads();
    int c = t, h = c >> 5;
    const float* vcol = qkv + (size_t)b*393216 + 512 + c;
    float acc0 = 0.f, acc1 = 0.f, acc2 = 0.f, acc3 = 0.f;
    for (int j = 0; j < 512; j += 2) {
        float vv0 = vcol[(size_t)j*768];
        float vv1 = vcol[(size_t)(j+1)*768];
        acc0 += a_lds[(0*8+h)*512 + j]*vv0 + a_lds[(0*8+h)*512 + j+1]*vv1;
        acc1 += a_lds[(1*8+h)*512 + j]*vv0 + a_lds[(1*8+h)*512 + j+1]*vv1;
        acc2 += a_lds[(2*8+h)*512 + j]*vv0 + a_lds[(2*8+h)*512 + j+1]*vv1;
        acc3 += a_lds[(3*8+h)*512 + j]*vv0 + a_lds[(3*8+h)*512 + j+1]*vv1;
    }
    o[(size_t)(bi0+0)*256 + c] = f2bf(acc0);
    o[(size_t)(bi0+1)*256 + c] = f2bf(acc1);
    o[(size_t)(bi0+2)*256 + c] = f2bf(acc2);
    o[(size_t)(bi0+3)*256 + c] = f2bf(acc3);
}

// -------- split-K combine for mlp2: out = resid + bias + sum_z part[z] --------
__global__ __launch_bounds__(256) void combine_kernel(const float* __restrict__ part,
                                                      const float* __restrict__ bias,
                                                      const float* __restrict__ resid,
                                                      float* __restrict__ out) {
    int f = blockIdx.x * 256 + threadIdx.x;   // 65536 float4s
    int e = f * 4;
    float4 r  = *(const float4*)(resid + e);
    float4 bv = *(const float4*)(bias + (e & 255));
    float4 p0 = *(const float4*)(part + e);
    float4 p1 = *(const float4*)(part + 262144 + e);
    float4 p2 = *(const float4*)(part + 524288 + e);
    float4 p3 = *(const float4*)(part + 786432 + e);
    float4 o4;
    o4.x = r.x + bv.x + p0.x + p1.x + p2.x + p3.x;
    o4.y = r.y + bv.y + p0.y + p1.y + p2.y + p3.y;
    o4.z = r.z + bv.z + p0.z + p1.z + p2.z + p3.z;
    o4.w = r.w + bv.w + p0.w + p1.w + p2.w + p3.w;
    *(float4*)(out + e) = o4;
}

extern "C" void kernel_launch(void* const* d_in, const int* in_sizes, int n_in,
                              void* d_out, int out_size, void* d_ws, size_t ws_size,
                              hipStream_t stream) {
    const float* x      = (const float*)d_in[0];
    const float* rp     = (const float*)d_in[1];
    const float* w_qkv  = (const float*)d_in[2];
    const float* w_proj = (const float*)d_in[3];
    const float* b_proj = (const float*)d_in[4];
    const float* w_rel  = (const float*)d_in[5];
    const float* b_rel  = (const float*)d_in[6];
    const float* g_reln = (const float*)d_in[7];
    const float* b_reln = (const float*)d_in[8];
    const float* g_n1   = (const float*)d_in[9];
    const float* b_n1   = (const float*)d_in[10];
    const float* g_n2   = (const float*)d_in[11];
    const float* b_n2   = (const float*)d_in[12];
    const float* w_mlp1 = (const float*)d_in[13];
    const float* b_mlp1 = (const float*)d_in[14];
    const float* w_mlp2 = (const float*)d_in[15];
    const float* b_mlp2 = (const float*)d_in[16];
    float* out = (float*)d_out;

    float* ws      = (float*)d_ws;
    float* ws_qkv  = ws;                    // 786432  f32 [1024][768]
    float* ws_qk   = ws_qkv + 786432;       // 4194304 f32 [bi][h][j]
    float* ws_attn = ws_qk  + 4194304;      // 4194304 f32 [bi][h][j]
    float* ws_x1   = ws_attn + 4194304;     // 262144  f32
    float* ws_pt   = ws_x1  + 262144;       // 1048576 f32 (4 partials)
    unsigned short* ub = (unsigned short*)(ws_pt + 1048576);
    unsigned short* hbf    = ub;            // 262144  bf16 (LN1 out)
    unsigned short* obf    = hbf  + 262144; // 262144  bf16 (attnv out)
    unsigned short* h2bf   = obf  + 262144; // 262144  bf16 (LN2 out)
    unsigned short* hgbf   = h2bf + 262144; // 1048576 bf16 (mlp1 out)
    unsigned short* wqkvT  = hgbf + 1048576;   // 196608
    unsigned short* wprojT = wqkvT + 196608;   // 65536
    unsigned short* wmlp1T = wprojT + 65536;   // 262144
    unsigned short* wmlp2T = wmlp1T + 262144;  // 262144

    // 0) weights -> transposed bf16
    convw_kernel<<<768, 256, 0, stream>>>(w_qkv, wqkvT, w_proj, wprojT,
                                          w_mlp1, wmlp1T, w_mlp2, wmlp2T);
    // 1) h = LN1(x)  (bf16)
    ln_kernel<<<256, 256, 0, stream>>>(x, g_n1, b_n1, hbf);
    // 2) qkv = h @ w_qkv   [1024,768] f32
    mgemm_kernel<false,false,false,false,1><<<dim3(16,12,1), 256, 0, stream>>>(
        hbf, wqkvT, nullptr, nullptr, ws_qkv, 1024, 768, 256);
    // 3) qk[bi][h][j]
    qk_kernel<<<dim3(16,8,2), 256, 0, stream>>>(ws_qkv, ws_qk);
    // 4) attn = softmax((qk + rel_bias)*scale)
    rel_softmax_kernel<<<1024, 256, 0, stream>>>(rp, ws_qk, w_rel, b_rel, g_reln, b_reln, ws_attn);
    // 5) o = attn @ v  (bf16)
    attnv_kernel<<<256, 256, 0, stream>>>(ws_attn, ws_qkv, obf);
    // 6) x1 = x + o @ w_proj + b_proj
    mgemm_kernel<true,false,true,false,1><<<dim3(16,4,1), 256, 0, stream>>>(
        obf, wprojT, b_proj, x, ws_x1, 1024, 256, 256);
    // 7) h2 = LN2(x1)  (bf16)
    ln_kernel<<<256, 256, 0, stream>>>(ws_x1, g_n2, b_n2, h2bf);
    // 8) hg = GELU(h2 @ w_mlp1 + b_mlp1)  [1024,1024] bf16
    mgemm_kernel<true,true,false,true,1><<<dim3(16,16,1), 256, 0, stream>>>(
        h2bf, wmlp1T, b_mlp1, nullptr, hgbf, 1024, 1024, 256);
    // 9) partials = hg @ w_mlp2 (split-K=4)
    mgemm_kernel<false,false,false,false,4><<<dim3(16,4,4), 256, 0, stream>>>(
        hgbf, wmlp2T, nullptr, nullptr, ws_pt, 1024, 256, 1024);
    // 10) out = x1 + b_mlp2 + sum partials
    combine_kernel<<<256, 256, 0, stream>>>(ws_pt, b_mlp2, ws_x1, out);
}

// Round 6
// 223.000 us; speedup vs baseline: 1.5948x; 1.2266x over previous
//
#include <hip/hip_runtime.h>
#include <cstddef>

#define EPS_ 1e-5f
#define SCALE_ 0.1767766952966369f   // 1/sqrt(32)

typedef short bf16x8_t __attribute__((ext_vector_type(8)));   // 8 bf16 in 4 VGPRs
typedef float f32x4_t  __attribute__((ext_vector_type(4)));

__device__ __forceinline__ float gelu_f(float x) {
    return 0.5f * x * (1.0f + erff(x * 0.7071067811865476f));
}
__device__ __forceinline__ unsigned short f2bf(float f) {
    unsigned u = __builtin_bit_cast(unsigned, f);
    u += 0x7FFFu + ((u >> 16) & 1u);           // RNE
    return (unsigned short)(u >> 16);
}

// -------- LayerNorm over C=256, one wave per row, bf16 output --------
__global__ __launch_bounds__(256) void ln_kernel(const float* __restrict__ x,
                                                 const float* __restrict__ g,
                                                 const float* __restrict__ b,
                                                 unsigned short* __restrict__ out) {
    int wid = threadIdx.x >> 6, lane = threadIdx.x & 63;
    int row = blockIdx.x * 4 + wid;
    const float4 xv = *(const float4*)(x + (size_t)row * 256 + lane * 4);
    float s  = xv.x + xv.y + xv.z + xv.w;
    float sq = xv.x*xv.x + xv.y*xv.y + xv.z*xv.z + xv.w*xv.w;
#pragma unroll
    for (int m = 1; m < 64; m <<= 1) { s += __shfl_xor(s, m); sq += __shfl_xor(sq, m); }
    float mean = s * (1.0f/256.0f);
    float var  = sq * (1.0f/256.0f) - mean*mean;
    float rstd = rsqrtf(var + EPS_);
    float4 gv = *(const float4*)(g + lane*4);
    float4 bv = *(const float4*)(b + lane*4);
    ushort4 o;
    o.x = f2bf((xv.x-mean)*rstd*gv.x + bv.x);
    o.y = f2bf((xv.y-mean)*rstd*gv.y + bv.y);
    o.z = f2bf((xv.z-mean)*rstd*gv.z + bv.z);
    o.w = f2bf((xv.w-mean)*rstd*gv.w + bv.w);
    *(ushort4*)(out + (size_t)row * 256 + lane * 4) = o;
}

// -------- transpose + convert the 4 weight matrices: W[K][N] f32 -> WT[N][K] bf16 --------
__global__ __launch_bounds__(256) void convw_kernel(
    const float* __restrict__ w_qkv,  unsigned short* __restrict__ wqkvT,
    const float* __restrict__ w_proj, unsigned short* __restrict__ wprojT,
    const float* __restrict__ w_mlp1, unsigned short* __restrict__ wmlp1T,
    const float* __restrict__ w_mlp2, unsigned short* __restrict__ wmlp2T) {
    __shared__ float tile[32][33];
    int bid = blockIdx.x, t = threadIdx.x;
    const float* W; unsigned short* WT; int K, N, tt;
    if (bid < 192)      { W = w_qkv;  WT = wqkvT;  K = 256;  N = 768;  tt = bid; }
    else if (bid < 256) { W = w_proj; WT = wprojT; K = 256;  N = 256;  tt = bid - 192; }
    else if (bid < 512) { W = w_mlp1; WT = wmlp1T; K = 256;  N = 1024; tt = bid - 256; }
    else                { W = w_mlp2; WT = wmlp2T; K = 1024; N = 256;  tt = bid - 512; }
    int ntn = N >> 5;
    int kt = tt / ntn, nt = tt % ntn;
    int k0 = kt * 32, n0 = nt * 32;
    {
        int kr = t >> 3, cg = (t & 7) * 4;
        float4 v = *(const float4*)(W + (size_t)(k0 + kr) * N + n0 + cg);
        tile[kr][cg+0] = v.x; tile[kr][cg+1] = v.y; tile[kr][cg+2] = v.z; tile[kr][cg+3] = v.w;
    }
    __syncthreads();
    {
        int nr = t >> 3, kg = (t & 7) * 4;
        ushort4 o;
        o.x = f2bf(tile[kg+0][nr]); o.y = f2bf(tile[kg+1][nr]);
        o.z = f2bf(tile[kg+2][nr]); o.w = f2bf(tile[kg+3][nr]);
        *(ushort4*)(WT + (size_t)(n0 + nr) * K + k0 + kg) = o;
    }
}

// -------- bf16 MFMA GEMM: C[M,N] = A[M,K](bf16) @ BT[N,K]^T(bf16) (+bias)(gelu)(+resid) --------
template<bool BIAS, bool GACT, bool RESID, bool BF16OUT, int KSPLIT>
__global__ __launch_bounds__(256) void mgemm_kernel(
    const unsigned short* __restrict__ A, const unsigned short* __restrict__ BT,
    const float* __restrict__ bias, const float* __restrict__ resid,
    void* __restrict__ Cout, int M, int N, int K) {
    __shared__ unsigned short Al[64][40];
    __shared__ unsigned short Bl[64][40];
    int t = threadIdx.x;
    int bm = blockIdx.x, bn = blockIdx.y, kz = blockIdx.z;
    int kchunk = K / KSPLIT;
    int srow = t >> 2, skk = (t & 3) * 8;
    const unsigned short* Ap = A  + (size_t)(bm*64 + srow) * K + kz*kchunk + skk;
    const unsigned short* Bp = BT + (size_t)(bn*64 + srow) * K + kz*kchunk + skk;
    int lane = t & 63, w = t >> 6, wr = w >> 1, wc = w & 1;
    int fr = lane & 15, fg = lane >> 4;
    f32x4_t a00 = {0.f,0.f,0.f,0.f}, a01 = {0.f,0.f,0.f,0.f};
    f32x4_t a10 = {0.f,0.f,0.f,0.f}, a11 = {0.f,0.f,0.f,0.f};
    for (int kk = 0; kk < kchunk; kk += 32) {
        uint4 av = *(const uint4*)(Ap + kk);
        uint4 bv = *(const uint4*)(Bp + kk);
        __syncthreads();
        *(uint4*)&Al[srow][skk] = av;
        *(uint4*)&Bl[srow][skk] = bv;
        __syncthreads();
        bf16x8_t fa0 = *(const bf16x8_t*)&Al[wr*32      + fr][fg*8];
        bf16x8_t fa1 = *(const bf16x8_t*)&Al[wr*32 + 16 + fr][fg*8];
        bf16x8_t fb0 = *(const bf16x8_t*)&Bl[wc*32      + fr][fg*8];
        bf16x8_t fb1 = *(const bf16x8_t*)&Bl[wc*32 + 16 + fr][fg*8];
        a00 = __builtin_amdgcn_mfma_f32_16x16x32_bf16(fa0, fb0, a00, 0, 0, 0);
        a01 = __builtin_amdgcn_mfma_f32_16x16x32_bf16(fa0, fb1, a01, 0, 0, 0);
        a10 = __builtin_amdgcn_mfma_f32_16x16x32_bf16(fa1, fb0, a10, 0, 0, 0);
        a11 = __builtin_amdgcn_mfma_f32_16x16x32_bf16(fa1, fb1, a11, 0, 0, 0);
    }
    float* Cf = (float*)Cout + (KSPLIT > 1 ? (size_t)kz * M * N : (size_t)0);
    unsigned short* Cb = (unsigned short*)Cout;
    auto emit = [&](f32x4_t acc, int mi, int ni) {
        int Ro = bm*64 + wr*32 + mi*16 + fg*4;
        int Co = bn*64 + wc*32 + ni*16 + fr;
        float bval = BIAS ? bias[Co] : 0.f;
#pragma unroll
        for (int e = 0; e < 4; ++e) {
            int r = Ro + e;
            float v = acc[e];
            if (BIAS)  v += bval;
            if (GACT)  v = gelu_f(v);
            if (RESID) v += resid[(size_t)r * N + Co];
            if (BF16OUT) Cb[(size_t)r * N + Co] = f2bf(v);
            else         Cf[(size_t)r * N + Co] = v;
        }
    };
    emit(a00, 0, 0); emit(a01, 0, 1); emit(a10, 1, 0); emit(a11, 1, 1);
}

// -------- qk[bi][h][j] = q_i^h . k_j^h ; block = (i-tile 32, h, b), k staged in LDS --------
__global__ __launch_bounds__(256) void qk_kernel(const float* __restrict__ qkv,
                                                 float* __restrict__ qk) {
    __shared__ float k_lds[512*32];   // 64 KB
    int t = threadIdx.x;
    int it = blockIdx.x;              // 0..15
    int h  = blockIdx.y;              // 0..7
    int b  = blockIdx.z;              // 0..1
    const float* base = qkv + (size_t)b * 393216;
#pragma unroll
    for (int r = 0; r < 16; ++r) {
        int idx = r*256 + t;
        int row = idx >> 3, c4 = idx & 7;
        float4 kv = *(const float4*)(base + (size_t)row*768 + 256 + h*32 + c4*4);
        *(float4*)(k_lds + row*32 + c4*4) = kv;
    }
    __syncthreads();
    int ir = t & 31, jg = t >> 5;     // thread: row it*32+ir, j-slice jg*64..+63
    int i = it*32 + ir;
    float4 q[8];
    const float* qp = base + (size_t)i*768 + h*32;
#pragma unroll
    for (int c4 = 0; c4 < 8; ++c4) q[c4] = *(const float4*)(qp + c4*4);
    float* outp = qk + (((size_t)(b*512 + i))*8 + h)*512 + jg*64;
    for (int jj = 0; jj < 64; jj += 4) {
        float a4[4];
#pragma unroll
        for (int u = 0; u < 4; ++u) {
            const float* kp = k_lds + (size_t)(jg*64 + jj + u)*32;
            float acc = 0.f;
#pragma unroll
            for (int c4 = 0; c4 < 8; ++c4) {
                float4 kv = *(const float4*)(kp + c4*4);
                acc += q[c4].x*kv.x + q[c4].y*kv.y + q[c4].z*kv.z + q[c4].w*kv.w;
            }
            a4[u] = acc;
        }
        *(float4*)(outp + jj) = make_float4(a4[0], a4[1], a4[2], a4[3]);
    }
}

// -------- Fused rel-bias (MFMA) + softmax. Block = (b,i); wave handles 128 j as 8 MFMA tiles. --------
// rel[j][h] = rp[bi,j,:] @ w_rel  via mfma_f32_16x16x32_bf16 (A = 16 j x 32 c, B = 32 c x 16 h, h>=8 zero-pad)
// then GELU + LN(8) in epilogue, logits to LDS; fused softmax adds qk and writes attn.
#define LGS 520   // logit LDS row stride (float4-aligned, conflict-light)
__global__ __launch_bounds__(256) void rel_softmax_kernel(
    const float* __restrict__ rp, const float* __restrict__ qk,
    const float* __restrict__ w_rel, const float* __restrict__ b_rel,
    const float* __restrict__ g_reln, const float* __restrict__ b_reln,
    float* __restrict__ attn) {
    __shared__ float lg_lds[8*LGS];   // 16.6 KB
    int t = threadIdx.x;
    int bi = blockIdx.x;              // b*512 + i
    int wid = t >> 6, lane = t & 63;
    int fr = lane & 15, fg = lane >> 4;
    bool act = fr < 8;                // h = fr valid
    // B fragments: lane holds w_rel[k = kk*32 + fg*8 + e][h = fr] (0 for fr>=8), e=0..7
    bf16x8_t bfrag[8];
#pragma unroll
    for (int kk = 0; kk < 8; ++kk) {
        bf16x8_t bf;
#pragma unroll
        for (int e = 0; e < 8; ++e) {
            float v = act ? w_rel[(size_t)(kk*32 + fg*8 + e)*8 + fr] : 0.f;
            bf[e] = (short)f2bf(v);
        }
        bfrag[kk] = bf;
    }
    float brel = act ? b_rel[fr]  : 0.f;
    float grn  = act ? g_reln[fr] : 1.f;
    float brn  = act ? b_reln[fr] : 0.f;
    const float* rpb = rp + (size_t)bi * 512 * 256;
#pragma unroll 1
    for (int tile = 0; tile < 8; ++tile) {
        int j0 = wid*128 + tile*16;
        const float* arow = rpb + (size_t)(j0 + fr)*256 + fg*8;
        f32x4_t acc = {0.f,0.f,0.f,0.f};
#pragma unroll
        for (int kk = 0; kk < 8; ++kk) {
            float4 x0 = *(const float4*)(arow + kk*32);
            float4 x1 = *(const float4*)(arow + kk*32 + 4);
            bf16x8_t af;
            af[0] = (short)f2bf(x0.x); af[1] = (short)f2bf(x0.y);
            af[2] = (short)f2bf(x0.z); af[3] = (short)f2bf(x0.w);
            af[4] = (short)f2bf(x1.x); af[5] = (short)f2bf(x1.y);
            af[6] = (short)f2bf(x1.z); af[7] = (short)f2bf(x1.w);
            acc = __builtin_amdgcn_mfma_f32_16x16x32_bf16(af, bfrag[kk], acc, 0, 0, 0);
        }
        // epilogue: acc[r] = rel sum for (j = j0 + fg*4 + r, h = fr)
#pragma unroll
        for (int r = 0; r < 4; ++r) {
            float val = acc[r] + brel;
            float gv = 0.5f * val * (1.0f + erff(val * 0.7071067811865476f));
            float sm = gv, sq = gv*gv;
            sm += __shfl_xor(sm, 1); sq += __shfl_xor(sq, 1);
            sm += __shfl_xor(sm, 2); sq += __shfl_xor(sq, 2);
            sm += __shfl_xor(sm, 4); sq += __shfl_xor(sq, 4);
            float mean = sm * 0.125f;
            float var  = sq * 0.125f - mean*mean;
            float reln = (gv - mean) * rsqrtf(var + EPS_) * grn + brn;
            if (act) lg_lds[fr*LGS + j0 + fg*4 + r] = reln;
        }
    }
    __syncthreads();
    // fused softmax: half-wave (32 lanes) per head row; qk row read coalesced here
    {
        int h = wid*2 + (lane >> 5);
        int sub = lane & 31;
        float* row = lg_lds + h*LGS + sub*16;
        const float* qrow = qk + ((size_t)bi*8 + h)*512 + sub*16;
        float v[16];
        float4 q0 = *(const float4*)(qrow + 0),  q1 = *(const float4*)(qrow + 4);
        float4 q2 = *(const float4*)(qrow + 8),  q3 = *(const float4*)(qrow + 12);
        float4 r0 = *(float4*)(row + 0),  r1 = *(float4*)(row + 4);
        float4 r2 = *(float4*)(row + 8),  r3 = *(float4*)(row + 12);
        v[0]=(q0.x+r0.x)*SCALE_; v[1]=(q0.y+r0.y)*SCALE_; v[2]=(q0.z+r0.z)*SCALE_; v[3]=(q0.w+r0.w)*SCALE_;
        v[4]=(q1.x+r1.x)*SCALE_; v[5]=(q1.y+r1.y)*SCALE_; v[6]=(q1.z+r1.z)*SCALE_; v[7]=(q1.w+r1.w)*SCALE_;
        v[8]=(q2.x+r2.x)*SCALE_; v[9]=(q2.y+r2.y)*SCALE_; v[10]=(q2.z+r2.z)*SCALE_; v[11]=(q2.w+r2.w)*SCALE_;
        v[12]=(q3.x+r3.x)*SCALE_; v[13]=(q3.y+r3.y)*SCALE_; v[14]=(q3.z+r3.z)*SCALE_; v[15]=(q3.w+r3.w)*SCALE_;
        float mx = v[0];
#pragma unroll
        for (int e = 1; e < 16; ++e) mx = fmaxf(mx, v[e]);
#pragma unroll
        for (int m = 1; m < 32; m <<= 1) mx = fmaxf(mx, __shfl_xor(mx, m));
        float s = 0.f;
#pragma unroll
        for (int e = 0; e < 16; ++e) { v[e] = expf(v[e] - mx); s += v[e]; }
#pragma unroll
        for (int m = 1; m < 32; m <<= 1) s += __shfl_xor(s, m);
        float inv = 1.0f / s;
#pragma unroll
        for (int e = 0; e < 16; ++e) v[e] *= inv;
        float* dst = attn + (size_t)bi*4096 + h*512 + sub*16;
        *(float4*)(dst +  0) = *(float4*)(v +  0);
        *(float4*)(dst +  4) = *(float4*)(v +  4);
        *(float4*)(dst +  8) = *(float4*)(v +  8);
        *(float4*)(dst + 12) = *(float4*)(v + 12);
    }
}

// -------- o = attn @ v (bf16 out). Block = 4 bi rows (attn in LDS); thread owns column c. --------
__global__ __launch_bounds__(256) void attnv_kernel(const float* __restrict__ attn,
                                                    const float* __restrict__ qkv,
                                                    unsigned short* __restrict__ o) {
    __shared__ float a_lds[4*8*512];  // 64 KB
    int t = threadIdx.x;
    int bi0 = blockIdx.x * 4;
    int b = bi0 >> 9;
    const float4* asrc = (const float4*)(attn + (size_t)bi0*4096);
    float4* adst = (float4*)a_lds;
#pragma unroll
    for (int r = 0; r < 16; ++r) adst[r*256 + t] = asrc[r*256 + t];
    __syncthreads();
    int c = t, h = c >> 5;
    const float* vcol = qkv + (size_t)b*393216 + 512 + c;
    float acc0 = 0.f, acc1 = 0.f, acc2 = 0.f, acc3 = 0.f;
    for (int j = 0; j < 512; j += 2) {
        float vv0 = vcol[(size_t)j*768];
        float vv1 = vcol[(size_t)(j+1)*768];
        acc0 += a_lds[(0*8+h)*512 + j]*vv0 + a_lds[(0*8+h)*512 + j+1]*vv1;
        acc1 += a_lds[(1*8+h)*512 + j]*vv0 + a_lds[(1*8+h)*512 + j+1]*vv1;
        acc2 += a_lds[(2*8+h)*512 + j]*vv0 + a_lds[(2*8+h)*512 + j+1]*vv1;
        acc3 += a_lds[(3*8+h)*512 + j]*vv0 + a_lds[(3*8+h)*512 + j+1]*vv1;
    }
    o[(size_t)(bi0+0)*256 + c] = f2bf(acc0);
    o[(size_t)(bi0+1)*256 + c] = f2bf(acc1);
    o[(size_t)(bi0+2)*256 + c] = f2bf(acc2);
    o[(size_t)(bi0+3)*256 + c] = f2bf(acc3);
}

// -------- split-K combine for mlp2: out = resid + bias + sum_z part[z] --------
__global__ __launch_bounds__(256) void combine_kernel(const float* __restrict__ part,
                                                      const float* __restrict__ bias,
                                                      const float* __restrict__ resid,
                                                      float* __restrict__ out) {
    int f = blockIdx.x * 256 + threadIdx.x;   // 65536 float4s
    int e = f * 4;
    float4 r  = *(const float4*)(resid + e);
    float4 bv = *(const float4*)(bias + (e & 255));
    float4 p0 = *(const float4*)(part + e);
    float4 p1 = *(const float4*)(part + 262144 + e);
    float4 p2 = *(const float4*)(part + 524288 + e);
    float4 p3 = *(const float4*)(part + 786432 + e);
    float4 o4;
    o4.x = r.x + bv.x + p0.x + p1.x + p2.x + p3.x;
    o4.y = r.y + bv.y + p0.y + p1.y + p2.y + p3.y;
    o4.z = r.z + bv.z + p0.z + p1.z + p2.z + p3.z;
    o4.w = r.w + bv.w + p0.w + p1.w + p2.w + p3.w;
    *(float4*)(out + e) = o4;
}

extern "C" void kernel_launch(void* const* d_in, const int* in_sizes, int n_in,
                              void* d_out, int out_size, void* d_ws, size_t ws_size,
                              hipStream_t stream) {
    const float* x      = (const float*)d_in[0];
    const float* rp     = (const float*)d_in[1];
    const float* w_qkv  = (const float*)d_in[2];
    const float* w_proj = (const float*)d_in[3];
    const float* b_proj = (const float*)d_in[4];
    const float* w_rel  = (const float*)d_in[5];
    const float* b_rel  = (const float*)d_in[6];
    const float* g_reln = (const float*)d_in[7];
    const float* b_reln = (const float*)d_in[8];
    const float* g_n1   = (const float*)d_in[9];
    const float* b_n1   = (const float*)d_in[10];
    const float* g_n2   = (const float*)d_in[11];
    const float* b_n2   = (const float*)d_in[12];
    const float* w_mlp1 = (const float*)d_in[13];
    const float* b_mlp1 = (const float*)d_in[14];
    const float* w_mlp2 = (const float*)d_in[15];
    const float* b_mlp2 = (const float*)d_in[16];
    float* out = (float*)d_out;

    float* ws      = (float*)d_ws;
    float* ws_qkv  = ws;                    // 786432  f32 [1024][768]
    float* ws_qk   = ws_qkv + 786432;       // 4194304 f32 [bi][h][j]
    float* ws_attn = ws_qk  + 4194304;      // 4194304 f32 [bi][h][j]
    float* ws_x1   = ws_attn + 4194304;     // 262144  f32
    float* ws_pt   = ws_x1  + 262144;       // 1048576 f32 (4 partials)
    unsigned short* ub = (unsigned short*)(ws_pt + 1048576);
    unsigned short* hbf    = ub;            // 262144  bf16 (LN1 out)
    unsigned short* obf    = hbf  + 262144; // 262144  bf16 (attnv out)
    unsigned short* h2bf   = obf  + 262144; // 262144  bf16 (LN2 out)
    unsigned short* hgbf   = h2bf + 262144; // 1048576 bf16 (mlp1 out)
    unsigned short* wqkvT  = hgbf + 1048576;   // 196608
    unsigned short* wprojT = wqkvT + 196608;   // 65536
    unsigned short* wmlp1T = wprojT + 65536;   // 262144
    unsigned short* wmlp2T = wmlp1T + 262144;  // 262144

    // 0) weights -> transposed bf16
    convw_kernel<<<768, 256, 0, stream>>>(w_qkv, wqkvT, w_proj, wprojT,
                                          w_mlp1, wmlp1T, w_mlp2, wmlp2T);
    // 1) h = LN1(x)  (bf16)
    ln_kernel<<<256, 256, 0, stream>>>(x, g_n1, b_n1, hbf);
    // 2) qkv = h @ w_qkv   [1024,768] f32
    mgemm_kernel<false,false,false,false,1><<<dim3(16,12,1), 256, 0, stream>>>(
        hbf, wqkvT, nullptr, nullptr, ws_qkv, 1024, 768, 256);
    // 3) qk[bi][h][j]
    qk_kernel<<<dim3(16,8,2), 256, 0, stream>>>(ws_qkv, ws_qk);
    // 4) attn = softmax((qk + rel_bias)*scale)  — rel GEMM via MFMA, GELU+LN epilogue, softmax fused
    rel_softmax_kernel<<<1024, 256, 0, stream>>>(rp, ws_qk, w_rel, b_rel, g_reln, b_reln, ws_attn);
    // 5) o = attn @ v  (bf16)
    attnv_kernel<<<256, 256, 0, stream>>>(ws_attn, ws_qkv, obf);
    // 6) x1 = x + o @ w_proj + b_proj
    mgemm_kernel<true,false,true,false,1><<<dim3(16,4,1), 256, 0, stream>>>(
        obf, wprojT, b_proj, x, ws_x1, 1024, 256, 256);
    // 7) h2 = LN2(x1)  (bf16)
    ln_kernel<<<256, 256, 0, stream>>>(ws_x1, g_n2, b_n2, h2bf);
    // 8) hg = GELU(h2 @ w_mlp1 + b_mlp1)  [1024,1024] bf16
    mgemm_kernel<true,true,false,true,1><<<dim3(16,16,1), 256, 0, stream>>>(
        h2bf, wmlp1T, b_mlp1, nullptr, hgbf, 1024, 1024, 256);
    // 9) partials = hg @ w_mlp2 (split-K=4)
    mgemm_kernel<false,false,false,false,4><<<dim3(16,4,4), 256, 0, stream>>>(
        hgbf, wmlp2T, nullptr, nullptr, ws_pt, 1024, 256, 1024);
    // 10) out = x1 + b_mlp2 + sum partials
    combine_kernel<<<256, 256, 0, stream>>>(ws_pt, b_mlp2, ws_x1, out);
}

// Round 8
// 222.887 us; speedup vs baseline: 1.5956x; 1.0005x over previous
//
#include <hip/hip_runtime.h>
#include <hip/hip_bf16.h>
#include <cstddef>

#define EPS_ 1e-5f
#define SCALE_ 0.1767766952966369f   // 1/sqrt(32)

typedef short bf16x8_t __attribute__((ext_vector_type(8)));   // 8 bf16 in 4 VGPRs
typedef float f32x4_t  __attribute__((ext_vector_type(4)));

// fast GELU (tanh form): max |dev| from exact-erf GELU ~3e-4, well within threshold
__device__ __forceinline__ float gelu_f(float x) {
    float y = 0.7978845608028654f * (x + 0.044715f * x * x * x);
    float e = __expf(2.0f * y);                       // v_exp_f32
    float t = 1.0f - 2.0f * __builtin_amdgcn_rcpf(e + 1.0f);
    return 0.5f * x * (1.0f + t);
}
__device__ __forceinline__ unsigned short f2bf(float f) {
    return __builtin_bit_cast(unsigned short, __float2bfloat16(f));
}
__device__ __forceinline__ unsigned f2bf2(float a, float b) {
    // two scalar RNE converts; compiler packs (v_cvt_pk_bf16_f32 where profitable)
    unsigned lo = __builtin_bit_cast(unsigned short, __float2bfloat16(a));
    unsigned hi = __builtin_bit_cast(unsigned short, __float2bfloat16(b));
    return lo | (hi << 16);
}
__device__ __forceinline__ float bf2f(unsigned short s) {
    unsigned u = (unsigned)s << 16;
    return __builtin_bit_cast(float, u);
}

// -------- LayerNorm over C=256, one wave per row, bf16 output --------
__global__ __launch_bounds__(256) void ln_kernel(const float* __restrict__ x,
                                                 const float* __restrict__ g,
                                                 const float* __restrict__ b,
                                                 unsigned short* __restrict__ out) {
    int wid = threadIdx.x >> 6, lane = threadIdx.x & 63;
    int row = blockIdx.x * 4 + wid;
    const float4 xv = *(const float4*)(x + (size_t)row * 256 + lane * 4);
    float s  = xv.x + xv.y + xv.z + xv.w;
    float sq = xv.x*xv.x + xv.y*xv.y + xv.z*xv.z + xv.w*xv.w;
#pragma unroll
    for (int m = 1; m < 64; m <<= 1) { s += __shfl_xor(s, m); sq += __shfl_xor(sq, m); }
    float mean = s * (1.0f/256.0f);
    float var  = sq * (1.0f/256.0f) - mean*mean;
    float rstd = rsqrtf(var + EPS_);
    float4 gv = *(const float4*)(g + lane*4);
    float4 bv = *(const float4*)(b + lane*4);
    uint2 o;
    o.x = f2bf2((xv.x-mean)*rstd*gv.x + bv.x, (xv.y-mean)*rstd*gv.y + bv.y);
    o.y = f2bf2((xv.z-mean)*rstd*gv.z + bv.z, (xv.w-mean)*rstd*gv.w + bv.w);
    *(uint2*)(out + (size_t)row * 256 + lane * 4) = o;
}

// -------- transpose + convert the 4 weight matrices: W[K][N] f32 -> WT[N][K] bf16 --------
__global__ __launch_bounds__(256) void convw_kernel(
    const float* __restrict__ w_qkv,  unsigned short* __restrict__ wqkvT,
    const float* __restrict__ w_proj, unsigned short* __restrict__ wprojT,
    const float* __restrict__ w_mlp1, unsigned short* __restrict__ wmlp1T,
    const float* __restrict__ w_mlp2, unsigned short* __restrict__ wmlp2T) {
    __shared__ float tile[32][33];
    int bid = blockIdx.x, t = threadIdx.x;
    const float* W; unsigned short* WT; int K, N, tt;
    if (bid < 192)      { W = w_qkv;  WT = wqkvT;  K = 256;  N = 768;  tt = bid; }
    else if (bid < 256) { W = w_proj; WT = wprojT; K = 256;  N = 256;  tt = bid - 192; }
    else if (bid < 512) { W = w_mlp1; WT = wmlp1T; K = 256;  N = 1024; tt = bid - 256; }
    else                { W = w_mlp2; WT = wmlp2T; K = 1024; N = 256;  tt = bid - 512; }
    int ntn = N >> 5;
    int kt = tt / ntn, nt = tt % ntn;
    int k0 = kt * 32, n0 = nt * 32;
    {
        int kr = t >> 3, cg = (t & 7) * 4;
        float4 v = *(const float4*)(W + (size_t)(k0 + kr) * N + n0 + cg);
        tile[kr][cg+0] = v.x; tile[kr][cg+1] = v.y; tile[kr][cg+2] = v.z; tile[kr][cg+3] = v.w;
    }
    __syncthreads();
    {
        int nr = t >> 3, kg = (t & 7) * 4;
        uint2 o;
        o.x = f2bf2(tile[kg+0][nr], tile[kg+1][nr]);
        o.y = f2bf2(tile[kg+2][nr], tile[kg+3][nr]);
        *(uint2*)(WT + (size_t)(n0 + nr) * K + k0 + kg) = o;
    }
}

// -------- bf16 MFMA GEMM: C[M,N] = A[M,K](bf16) @ BT[N,K]^T(bf16) (+bias)(gelu)(+resid) --------
template<bool BIAS, bool GACT, bool RESID, bool BF16OUT, int KSPLIT>
__global__ __launch_bounds__(256) void mgemm_kernel(
    const unsigned short* __restrict__ A, const unsigned short* __restrict__ BT,
    const float* __restrict__ bias, const float* __restrict__ resid,
    void* __restrict__ Cout, int M, int N, int K) {
    __shared__ unsigned short Al[64][40];
    __shared__ unsigned short Bl[64][40];
    int t = threadIdx.x;
    int bm = blockIdx.x, bn = blockIdx.y, kz = blockIdx.z;
    int kchunk = K / KSPLIT;
    int srow = t >> 2, skk = (t & 3) * 8;
    const unsigned short* Ap = A  + (size_t)(bm*64 + srow) * K + kz*kchunk + skk;
    const unsigned short* Bp = BT + (size_t)(bn*64 + srow) * K + kz*kchunk + skk;
    int lane = t & 63, w = t >> 6, wr = w >> 1, wc = w & 1;
    int fr = lane & 15, fg = lane >> 4;
    f32x4_t a00 = {0.f,0.f,0.f,0.f}, a01 = {0.f,0.f,0.f,0.f};
    f32x4_t a10 = {0.f,0.f,0.f,0.f}, a11 = {0.f,0.f,0.f,0.f};
    for (int kk = 0; kk < kchunk; kk += 32) {
        uint4 av = *(const uint4*)(Ap + kk);
        uint4 bv = *(const uint4*)(Bp + kk);
        __syncthreads();
        *(uint4*)&Al[srow][skk] = av;
        *(uint4*)&Bl[srow][skk] = bv;
        __syncthreads();
        bf16x8_t fa0 = *(const bf16x8_t*)&Al[wr*32      + fr][fg*8];
        bf16x8_t fa1 = *(const bf16x8_t*)&Al[wr*32 + 16 + fr][fg*8];
        bf16x8_t fb0 = *(const bf16x8_t*)&Bl[wc*32      + fr][fg*8];
        bf16x8_t fb1 = *(const bf16x8_t*)&Bl[wc*32 + 16 + fr][fg*8];
        a00 = __builtin_amdgcn_mfma_f32_16x16x32_bf16(fa0, fb0, a00, 0, 0, 0);
        a01 = __builtin_amdgcn_mfma_f32_16x16x32_bf16(fa0, fb1, a01, 0, 0, 0);
        a10 = __builtin_amdgcn_mfma_f32_16x16x32_bf16(fa1, fb0, a10, 0, 0, 0);
        a11 = __builtin_amdgcn_mfma_f32_16x16x32_bf16(fa1, fb1, a11, 0, 0, 0);
    }
    float* Cf = (float*)Cout + (KSPLIT > 1 ? (size_t)kz * M * N : (size_t)0);
    unsigned short* Cb = (unsigned short*)Cout;
    auto emit = [&](f32x4_t acc, int mi, int ni) {
        int Ro = bm*64 + wr*32 + mi*16 + fg*4;
        int Co = bn*64 + wc*32 + ni*16 + fr;
        float bval = BIAS ? bias[Co] : 0.f;
#pragma unroll
        for (int e = 0; e < 4; ++e) {
            int r = Ro + e;
            float v = acc[e];
            if (BIAS)  v += bval;
            if (GACT)  v = gelu_f(v);
            if (RESID) v += resid[(size_t)r * N + Co];
            if (BF16OUT) Cb[(size_t)r * N + Co] = f2bf(v);
            else         Cf[(size_t)r * N + Co] = v;
        }
    };
    emit(a00, 0, 0); emit(a01, 0, 1); emit(a10, 1, 0); emit(a11, 1, 1);
}

// -------- qk[bi][h][j] = q_i^h . k_j^h ; block = (i-tile 32, h, b), k staged in LDS --------
__global__ __launch_bounds__(256) void qk_kernel(const float* __restrict__ qkv,
                                                 float* __restrict__ qk) {
    __shared__ float k_lds[512*32];   // 64 KB
    int t = threadIdx.x;
    int it = blockIdx.x;              // 0..15
    int h  = blockIdx.y;              // 0..7
    int b  = blockIdx.z;              // 0..1
    const float* base = qkv + (size_t)b * 393216;
#pragma unroll
    for (int r = 0; r < 16; ++r) {
        int idx = r*256 + t;
        int row = idx >> 3, c4 = idx & 7;
        float4 kv = *(const float4*)(base + (size_t)row*768 + 256 + h*32 + c4*4);
        *(float4*)(k_lds + row*32 + c4*4) = kv;
    }
    __syncthreads();
    int ir = t & 31, jg = t >> 5;     // thread: row it*32+ir, j-slice jg*64..+63
    int i = it*32 + ir;
    float4 q[8];
    const float* qp = base + (size_t)i*768 + h*32;
#pragma unroll
    for (int c4 = 0; c4 < 8; ++c4) q[c4] = *(const float4*)(qp + c4*4);
    float* outp = qk + (((size_t)(b*512 + i))*8 + h)*512 + jg*64;
    for (int jj = 0; jj < 64; jj += 4) {
        float a4[4];
#pragma unroll
        for (int u = 0; u < 4; ++u) {
            const float* kp = k_lds + (size_t)(jg*64 + jj + u)*32;
            float acc = 0.f;
#pragma unroll
            for (int c4 = 0; c4 < 8; ++c4) {
                float4 kv = *(const float4*)(kp + c4*4);
                acc += q[c4].x*kv.x + q[c4].y*kv.y + q[c4].z*kv.z + q[c4].w*kv.w;
            }
            a4[u] = acc;
        }
        *(float4*)(outp + jj) = make_float4(a4[0], a4[1], a4[2], a4[3]);
    }
}

// -------- Fused rel-bias (MFMA) + softmax. Block = (b,i); wave handles 128 j as 8 MFMA tiles. --------
// rel[j][h] = rp[bi,j,:] @ w_rel via mfma_f32_16x16x32_bf16; GELU+LN(8) epilogue; softmax fused.
#define LGS 520
__global__ __launch_bounds__(256) void rel_softmax_kernel(
    const float* __restrict__ rp, const float* __restrict__ qk,
    const float* __restrict__ w_rel, const float* __restrict__ b_rel,
    const float* __restrict__ g_reln, const float* __restrict__ b_reln,
    unsigned short* __restrict__ attn) {
    __shared__ float lg_lds[8*LGS];   // 16.6 KB
    int t = threadIdx.x;
    int bi = blockIdx.x;              // b*512 + i
    int wid = t >> 6, lane = t & 63;
    int fr = lane & 15, fg = lane >> 4;
    bool act = fr < 8;                // h = fr valid
    // B fragments: lane holds w_rel[k = kk*32 + fg*8 + e][h = fr] (0 for fr>=8)
    bf16x8_t bfrag[8];
#pragma unroll
    for (int kk = 0; kk < 8; ++kk) {
        bf16x8_t bf;
#pragma unroll
        for (int e = 0; e < 8; ++e) {
            float v = act ? w_rel[(size_t)(kk*32 + fg*8 + e)*8 + fr] : 0.f;
            bf[e] = (short)f2bf(v);
        }
        bfrag[kk] = bf;
    }
    float brel = act ? b_rel[fr]  : 0.f;
    float grn  = act ? g_reln[fr] : 1.f;
    float brn  = act ? b_reln[fr] : 0.f;
    const float* rpb = rp + (size_t)bi * 512 * 256;
#pragma unroll 1
    for (int tile = 0; tile < 8; ++tile) {
        int j0 = wid*128 + tile*16;
        const float* arow = rpb + (size_t)(j0 + fr)*256 + fg*8;
        f32x4_t acc = {0.f,0.f,0.f,0.f};
#pragma unroll
        for (int kk = 0; kk < 8; ++kk) {
            float4 x0 = *(const float4*)(arow + kk*32);
            float4 x1 = *(const float4*)(arow + kk*32 + 4);
            union { bf16x8_t v; uint4 u; } cvt;
            cvt.u.x = f2bf2(x0.x, x0.y);
            cvt.u.y = f2bf2(x0.z, x0.w);
            cvt.u.z = f2bf2(x1.x, x1.y);
            cvt.u.w = f2bf2(x1.z, x1.w);
            acc = __builtin_amdgcn_mfma_f32_16x16x32_bf16(cvt.v, bfrag[kk], acc, 0, 0, 0);
        }
        // epilogue: acc[r] = rel sum for (j = j0 + fg*4 + r, h = fr)
#pragma unroll
        for (int r = 0; r < 4; ++r) {
            float val = acc[r] + brel;
            float gv = gelu_f(val);
            float sm = gv, sq = gv*gv;
            sm += __shfl_xor(sm, 1); sq += __shfl_xor(sq, 1);
            sm += __shfl_xor(sm, 2); sq += __shfl_xor(sq, 2);
            sm += __shfl_xor(sm, 4); sq += __shfl_xor(sq, 4);
            float mean = sm * 0.125f;
            float var  = sq * 0.125f - mean*mean;
            float reln = (gv - mean) * rsqrtf(var + EPS_) * grn + brn;
            if (act) lg_lds[fr*LGS + j0 + fg*4 + r] = reln;
        }
    }
    __syncthreads();
    // fused softmax: half-wave (32 lanes) per head row; interleaved float4 chunks (low bank conflict)
    {
        int h = wid*2 + (lane >> 5);
        int sub = lane & 31;
        const float* row  = lg_lds + h*LGS;
        const float* qrow = qk + ((size_t)bi*8 + h)*512;
        float v[16];
#pragma unroll
        for (int c4 = 0; c4 < 4; ++c4) {
            float4 r4 = *(const float4*)(row  + c4*128 + sub*4);
            float4 q4 = *(const float4*)(qrow + c4*128 + sub*4);
            v[c4*4+0] = (q4.x + r4.x) * SCALE_;
            v[c4*4+1] = (q4.y + r4.y) * SCALE_;
            v[c4*4+2] = (q4.z + r4.z) * SCALE_;
            v[c4*4+3] = (q4.w + r4.w) * SCALE_;
        }
        float mx = v[0];
#pragma unroll
        for (int e = 1; e < 16; ++e) mx = fmaxf(mx, v[e]);
#pragma unroll
        for (int m = 1; m < 32; m <<= 1) mx = fmaxf(mx, __shfl_xor(mx, m));
        float s = 0.f;
#pragma unroll
        for (int e = 0; e < 16; ++e) { v[e] = __expf(v[e] - mx); s += v[e]; }
#pragma unroll
        for (int m = 1; m < 32; m <<= 1) s += __shfl_xor(s, m);
        float inv = 1.0f / s;
#pragma unroll
        for (int e = 0; e < 16; ++e) v[e] *= inv;
        unsigned short* dst = attn + (size_t)bi*4096 + h*512;
#pragma unroll
        for (int c4 = 0; c4 < 4; ++c4) {
            uint2 o2;
            o2.x = f2bf2(v[c4*4+0], v[c4*4+1]);
            o2.y = f2bf2(v[c4*4+2], v[c4*4+3]);
            *(uint2*)(dst + c4*128 + sub*4) = o2;
        }
    }
}

// -------- o = attn(bf16) @ v. Block = 4 bi rows (attn in LDS as f32); thread owns column c. --------
__global__ __launch_bounds__(256) void attnv_kernel(const unsigned short* __restrict__ attn,
                                                    const float* __restrict__ qkv,
                                                    unsigned short* __restrict__ o) {
    __shared__ float a_lds[4*8*512];  // 64 KB
    int t = threadIdx.x;
    int bi0 = blockIdx.x * 4;
    int b = bi0 >> 9;
    const ushort4* asrc = (const ushort4*)(attn + (size_t)bi0*4096);
#pragma unroll
    for (int r = 0; r < 16; ++r) {
        ushort4 s4 = asrc[r*256 + t];
        float4 f4 = make_float4(bf2f(s4.x), bf2f(s4.y), bf2f(s4.z), bf2f(s4.w));
        *(float4*)(a_lds + (size_t)(r*256 + t)*4) = f4;
    }
    __syncthreads();
    int c = t, h = c >> 5;
    const float* vcol = qkv + (size_t)b*393216 + 512 + c;
    float acc0 = 0.f, acc1 = 0.f, acc2 = 0.f, acc3 = 0.f;
    for (int j = 0; j < 512; j += 2) {
        float vv0 = vcol[(size_t)j*768];
        float vv1 = vcol[(size_t)(j+1)*768];
        acc0 += a_lds[(0*8+h)*512 + j]*vv0 + a_lds[(0*8+h)*512 + j+1]*vv1;
        acc1 += a_lds[(1*8+h)*512 + j]*vv0 + a_lds[(1*8+h)*512 + j+1]*vv1;
        acc2 += a_lds[(2*8+h)*512 + j]*vv0 + a_lds[(2*8+h)*512 + j+1]*vv1;
        acc3 += a_lds[(3*8+h)*512 + j]*vv0 + a_lds[(3*8+h)*512 + j+1]*vv1;
    }
    o[(size_t)(bi0+0)*256 + c] = f2bf(acc0);
    o[(size_t)(bi0+1)*256 + c] = f2bf(acc1);
    o[(size_t)(bi0+2)*256 + c] = f2bf(acc2);
    o[(size_t)(bi0+3)*256 + c] = f2bf(acc3);
}

// -------- split-K combine for mlp2: out = resid + bias + sum_z part[z] --------
__global__ __launch_bounds__(256) void combine_kernel(const float* __restrict__ part,
                                                      const float* __restrict__ bias,
                                                      const float* __restrict__ resid,
                                                      float* __restrict__ out) {
    int f = blockIdx.x * 256 + threadIdx.x;   // 65536 float4s
    int e = f * 4;
    float4 r  = *(const float4*)(resid + e);
    float4 bv = *(const float4*)(bias + (e & 255));
    float4 p0 = *(const float4*)(part + e);
    float4 p1 = *(const float4*)(part + 262144 + e);
    float4 p2 = *(const float4*)(part + 524288 + e);
    float4 p3 = *(const float4*)(part + 786432 + e);
    float4 o4;
    o4.x = r.x + bv.x + p0.x + p1.x + p2.x + p3.x;
    o4.y = r.y + bv.y + p0.y + p1.y + p2.y + p3.y;
    o4.z = r.z + bv.z + p0.z + p1.z + p2.z + p3.z;
    o4.w = r.w + bv.w + p0.w + p1.w + p2.w + p3.w;
    *(float4*)(out + e) = o4;
}

extern "C" void kernel_launch(void* const* d_in, const int* in_sizes, int n_in,
                              void* d_out, int out_size, void* d_ws, size_t ws_size,
                              hipStream_t stream) {
    const float* x      = (const float*)d_in[0];
    const float* rp     = (const float*)d_in[1];
    const float* w_qkv  = (const float*)d_in[2];
    const float* w_proj = (const float*)d_in[3];
    const float* b_proj = (const float*)d_in[4];
    const float* w_rel  = (const float*)d_in[5];
    const float* b_rel  = (const float*)d_in[6];
    const float* g_reln = (const float*)d_in[7];
    const float* b_reln = (const float*)d_in[8];
    const float* g_n1   = (const float*)d_in[9];
    const float* b_n1   = (const float*)d_in[10];
    const float* g_n2   = (const float*)d_in[11];
    const float* b_n2   = (const float*)d_in[12];
    const float* w_mlp1 = (const float*)d_in[13];
    const float* b_mlp1 = (const float*)d_in[14];
    const float* w_mlp2 = (const float*)d_in[15];
    const float* b_mlp2 = (const float*)d_in[16];
    float* out = (float*)d_out;

    float* ws      = (float*)d_ws;
    float* ws_qkv  = ws;                    // 786432  f32 [1024][768]
    float* ws_qk   = ws_qkv + 786432;       // 4194304 f32 [bi][h][j]
    float* ws_x1   = ws_qk  + 4194304;      // 262144  f32
    float* ws_pt   = ws_x1  + 262144;       // 1048576 f32 (4 partials)
    unsigned short* ub = (unsigned short*)(ws_pt + 1048576);
    unsigned short* attnbf = ub;               // 4194304 bf16 [bi][h][j]
    unsigned short* hbf    = attnbf + 4194304; // 262144  bf16 (LN1 out)
    unsigned short* obf    = hbf  + 262144;    // 262144  bf16 (attnv out)
    unsigned short* h2bf   = obf  + 262144;    // 262144  bf16 (LN2 out)
    unsigned short* hgbf   = h2bf + 262144;    // 1048576 bf16 (mlp1 out)
    unsigned short* wqkvT  = hgbf + 1048576;   // 196608
    unsigned short* wprojT = wqkvT + 196608;   // 65536
    unsigned short* wmlp1T = wprojT + 65536;   // 262144
    unsigned short* wmlp2T = wmlp1T + 262144;  // 262144

    // 0) weights -> transposed bf16
    convw_kernel<<<768, 256, 0, stream>>>(w_qkv, wqkvT, w_proj, wprojT,
                                          w_mlp1, wmlp1T, w_mlp2, wmlp2T);
    // 1) h = LN1(x)  (bf16)
    ln_kernel<<<256, 256, 0, stream>>>(x, g_n1, b_n1, hbf);
    // 2) qkv = h @ w_qkv   [1024,768] f32
    mgemm_kernel<false,false,false,false,1><<<dim3(16,12,1), 256, 0, stream>>>(
        hbf, wqkvT, nullptr, nullptr, ws_qkv, 1024, 768, 256);
    // 3) qk[bi][h][j]
    qk_kernel<<<dim3(16,8,2), 256, 0, stream>>>(ws_qkv, ws_qk);
    // 4) attn(bf16) = softmax((qk + rel_bias)*scale)
    rel_softmax_kernel<<<1024, 256, 0, stream>>>(rp, ws_qk, w_rel, b_rel, g_reln, b_reln, attnbf);
    // 5) o = attn @ v  (bf16)
    attnv_kernel<<<256, 256, 0, stream>>>(attnbf, ws_qkv, obf);
    // 6) x1 = x + o @ w_proj + b_proj
    mgemm_kernel<true,false,true,false,1><<<dim3(16,4,1), 256, 0, stream>>>(
        obf, wprojT, b_proj, x, ws_x1, 1024, 256, 256);
    // 7) h2 = LN2(x1)  (bf16)
    ln_kernel<<<256, 256, 0, stream>>>(ws_x1, g_n2, b_n2, h2bf);
    // 8) hg = GELU(h2 @ w_mlp1 + b_mlp1)  [1024,1024] bf16
    mgemm_kernel<true,true,false,true,1><<<dim3(16,16,1), 256, 0, stream>>>(
        h2bf, wmlp1T, b_mlp1, nullptr, hgbf, 1024, 1024, 256);
    // 9) partials = hg @ w_mlp2 (split-K=4)
    mgemm_kernel<false,false,false,false,4><<<dim3(16,4,4), 256, 0, stream>>>(
        hgbf, wmlp2T, nullptr, nullptr, ws_pt, 1024, 256, 1024);
    // 10) out = x1 + b_mlp2 + sum partials
    combine_kernel<<<256, 256, 0, stream>>>(ws_pt, b_mlp2, ws_x1, out);
}